// Round 10
// baseline (579.776 us; speedup 1.0000x reference)
//
#include <hip/hip_runtime.h>

// ---------------------------------------------------------------------------
// RPN forward: conv3x3(512->512)+relu, 1x1 heads (18 cls, 36 bbox),
// anchor decode + clip, softmax score, greedy NMS (0.7), keep-masked boxes.
// All decision math in fp32 with contraction OFF to track the numpy reference.
// R10: conv_gemm = R8's 64x64/4x4 tile (181us best) + 2-phase double-buffer
//   (1 barrier/iter instead of 2; next tile's global loads issued before
//   compute, written to the other LDS buffer after) + Bt pad 64->68 (old
//   B-stage ds_write_b128 was 8-way bank conflict). FMA order unchanged.
//   R9's 128x64/8x4 regressed (216us): A-write 4-way conflicts (8.8M cy),
//   occupancy 31->20%. NMS: R8 sparse lists + 1-wave scan (kept).
// ---------------------------------------------------------------------------

#define NBATCH 4
#define HWDIM  25
#define NPOS   625            // 25*25
#define NM     2500           // NBATCH*NPOS
#define CIN    512
#define NANCH  5625           // NPOS*9
#define NW     88             // ceil(NANCH/64)
#define CAP    4096           // list capacity per (b, colword)

typedef unsigned long long u64;
typedef unsigned int u32;

struct BaseAnchors { float x1[9], y1[9], x2[9], y2[9]; };

__device__ __forceinline__ u64 bcast64(u64 v, int lane) {
  unsigned int lo = (unsigned int)v;
  unsigned int hi = (unsigned int)(v >> 32);
  lo = (unsigned int)__builtin_amdgcn_readlane((int)lo, lane);
  hi = (unsigned int)__builtin_amdgcn_readlane((int)hi, lane);
  return (((u64)hi) << 32) | (u64)lo;
}

__device__ __forceinline__ u64 waveOr64(u64 x) {
  unsigned int lo = (unsigned int)x, hi = (unsigned int)(x >> 32);
#pragma unroll
  for (int off = 32; off > 0; off >>= 1) {
    lo |= (unsigned int)__shfl_xor((int)lo, off, 64);
    hi |= (unsigned int)__shfl_xor((int)hi, off, 64);
  }
  return (((u64)hi) << 32) | (u64)lo;
}

// --------------------------- prep: transposes ------------------------------

// f[b][c][pos] -> fm[b*625+pos][c]
__global__ void transpose_features(const float* __restrict__ f, float* __restrict__ fm) {
  __shared__ float tile[32][33];
  int b  = blockIdx.z;
  int p0 = blockIdx.x * 32;
  int c0 = blockIdx.y * 32;
  int tx = threadIdx.x, ty = threadIdx.y;  // (32, 8)
#pragma unroll
  for (int j = 0; j < 4; j++) {
    int c = c0 + ty + j * 8;
    int p = p0 + tx;
    if (p < NPOS) tile[ty + j * 8][tx] = f[((size_t)(b * CIN + c)) * NPOS + p];
  }
  __syncthreads();
#pragma unroll
  for (int j = 0; j < 4; j++) {
    int p = p0 + ty + j * 8;
    int c = c0 + tx;
    if (p < NPOS) fm[((size_t)(b * NPOS + p)) * CIN + c] = tile[tx][ty + j * 8];
  }
}

// conv_w[o][c][tap] -> Wt[tap][c][o]
__global__ __launch_bounds__(256) void transpose_weights(const float* __restrict__ cw,
                                                         float* __restrict__ Wt) {
  __shared__ float tile[32][289];
  int o0 = blockIdx.x * 32, c0 = blockIdx.y * 32;
  int tid = threadIdx.x;
#pragma unroll
  for (int j = 0; j < 36; j++) {
    int idx = tid + j * 256;            // 0..9215
    int o = idx / 288, kk = idx % 288;  // kk = c_rel*9 + tap
    tile[o][kk] = cw[((size_t)(o0 + o)) * 4608 + c0 * 9 + kk];
  }
  __syncthreads();
  int ol = tid & 31, pg = tid >> 5;  // 0..7
#pragma unroll
  for (int j = 0; j < 36; j++) {
    int pair = pg + j * 8;  // 0..287 == c_rel*9 + tap
    int c = pair / 9, tap = pair % 9;
    Wt[((size_t)tap * CIN + (c0 + c)) * 512 + o0 + ol] = tile[ol][pair];
  }
}

// combined 1x1 head weights: Wco[c][o] (o: 0..17 cls, 18..53 bbox, 54..63 zero)
__global__ void build_wco(const float* __restrict__ clsw, const float* __restrict__ clsb,
                          const float* __restrict__ bw, const float* __restrict__ bbb,
                          float* __restrict__ Wco, float* __restrict__ bco) {
  int idx = blockIdx.x * 256 + threadIdx.x;
  if (idx < 512 * 64) {
    int c = idx >> 6, o = idx & 63;
    float v = 0.f;
    if (o < 18) v = clsw[o * 512 + c];
    else if (o < 54) v = bw[(o - 18) * 512 + c];
    Wco[idx] = v;
  }
  if (idx < 64) {
    float v = 0.f;
    if (idx < 18) v = clsb[idx];
    else if (idx < 54) v = bbb[idx - 18];
    bco[idx] = v;
  }
}

__global__ void zero_cnt(u32* __restrict__ cnt) {
  int i = blockIdx.x * 64 + threadIdx.x;
  if (i < NBATCH * NW) cnt[i] = 0u;
}

// --------------------------- conv3x3 implicit GEMM -------------------------
// grid (40, 8, 3): 64 m-rows x 64 o-cols per block, part = 3 taps (dy fixed).
// 2-phase pipelined: iter it in [0,48) = (tap tt=it>>4, c0=(it&15)*32).
// Issue loads(it+1) -> compute LDS[it&1] -> write LDS[(it&1)^1] -> barrier.
// Writes partial sums (no bias/relu) to xp[part][m][o]. FMA order == R8.
__global__ __launch_bounds__(256) void conv_gemm(const float* __restrict__ fm,
                                                 const float* __restrict__ Wt,
                                                 float* __restrict__ xp) {
  __shared__ __align__(16) float At[2][32][68];
  __shared__ __align__(16) float Bt[2][32][68];  // pad 68: B-stage write was 8-way conflict at 64
  int tid = threadIdx.x;
  int m0 = blockIdx.x << 6;
  int o0 = blockIdx.y << 6;
  int part = blockIdx.z;  // 0..2 -> dy = part-1
  int ti = tid >> 4, tj = tid & 15;   // compute tile 4x4
  int si = tid >> 2, sq = tid & 3;    // A staging: row si, col quad sq
  int skk = tid >> 3, sr = tid & 7;   // B staging: k-row skk, col oct sr
  float acc[4][4] = {{0.f}};

  int m = m0 + si;
  bool mv = m < NM;
  int mm = mv ? m : 0;
  int bb = mm / NPOS, rem = mm % NPOS;
  int hh = rem / HWDIM, ww = rem % HWDIM;
  int dy = part - 1;

  // per-tap A row pointer and validity (dx = tt-1)
  const float* arowp[3];
  bool avv[3];
#pragma unroll
  for (int tt = 0; tt < 3; tt++) {
    int h2 = hh + dy, w2 = ww + (tt - 1);
    bool av = mv && ((unsigned)h2 < (unsigned)HWDIM) && ((unsigned)w2 < (unsigned)HWDIM);
    avv[tt] = av;
    arowp[tt] = fm + (((size_t)(bb * NPOS + (av ? h2 * HWDIM + w2 : 0))) << 9) + (sq << 2);
  }

  auto loadTile = [&](int it, float4& a0, float4& a1, float4& b0, float4& b1) {
    int tt = it >> 4;
    int cc = (it & 15) << 5;
    a0 = make_float4(0.f, 0.f, 0.f, 0.f);
    a1 = a0;
    if (avv[tt]) {
      const float* p = arowp[tt] + cc;
      a0 = *(const float4*)p;
      a1 = *(const float4*)(p + 16);
    }
    const float* bp = Wt + (((size_t)(part * 3 + tt)) << 18) + o0 +
                      (((size_t)(cc + skk)) << 9) + (sr << 2);
    b0 = *(const float4*)bp;
    b1 = *(const float4*)(bp + 32);
  };
  auto writeTile = [&](int buf, float4 a0, float4 a1, float4 b0, float4 b1) {
    int kb = sq << 2;
    At[buf][kb + 0][si] = a0.x; At[buf][kb + 1][si] = a0.y;
    At[buf][kb + 2][si] = a0.z; At[buf][kb + 3][si] = a0.w;
    At[buf][kb + 16][si] = a1.x; At[buf][kb + 17][si] = a1.y;
    At[buf][kb + 18][si] = a1.z; At[buf][kb + 19][si] = a1.w;
    *(float4*)&Bt[buf][skk][sr << 2] = b0;
    *(float4*)&Bt[buf][skk][32 + (sr << 2)] = b1;
  };

  {
    float4 a0, a1, b0, b1;
    loadTile(0, a0, a1, b0, b1);
    writeTile(0, a0, a1, b0, b1);
  }
  __syncthreads();

  for (int it = 0; it < 48; it++) {
    int cur = it & 1;
    float4 na0, na1, nb0, nb1;
    bool hasNext = (it + 1 < 48);
    if (hasNext) loadTile(it + 1, na0, na1, nb0, nb1);  // in flight under compute
#pragma unroll
    for (int kk = 0; kk < 32; kk++) {
      float4 avv4 = *(const float4*)&At[cur][kk][ti << 2];
      float4 bvv4 = *(const float4*)&Bt[cur][kk][tj << 2];
      float a_[4] = {avv4.x, avv4.y, avv4.z, avv4.w};
      float b_[4] = {bvv4.x, bvv4.y, bvv4.z, bvv4.w};
#pragma unroll
      for (int u = 0; u < 4; u++)
#pragma unroll
        for (int v = 0; v < 4; v++) acc[u][v] += a_[u] * b_[v];
    }
    if (hasNext) writeTile(cur ^ 1, na0, na1, nb0, nb1);
    __syncthreads();
  }

  float* outp = xp + (size_t)part * (NM * 512);
#pragma unroll
  for (int u = 0; u < 4; u++) {
    int mr = m0 + (ti << 2) + u;
    if (mr < NM) {
      *(float4*)(outp + (((size_t)mr) << 9) + o0 + (tj << 2)) =
          make_float4(acc[u][0], acc[u][1], acc[u][2], acc[u][3]);
    }
  }
}

// x2 = relu(xp0+xp1+xp2+bias)
__global__ void combine_relu(const float* __restrict__ xp, const float* __restrict__ bias,
                             float* __restrict__ x2) {
  int i4 = blockIdx.x * 256 + threadIdx.x;  // over 320000 float4s
  if (i4 >= NM * 128) return;
  float4 p0 = *(const float4*)(xp + (size_t)i4 * 4);
  float4 p1 = *(const float4*)(xp + (size_t)(NM * 512) + (size_t)i4 * 4);
  float4 p2 = *(const float4*)(xp + (size_t)(2 * NM * 512) + (size_t)i4 * 4);
  float4 bb = *(const float4*)(bias + (i4 & 127) * 4);
  float4 r;
  r.x = fmaxf(p0.x + p1.x + p2.x + bb.x, 0.f);
  r.y = fmaxf(p0.y + p1.y + p2.y + bb.y, 0.f);
  r.z = fmaxf(p0.z + p1.z + p2.z + bb.z, 0.f);
  r.w = fmaxf(p0.w + p1.w + p2.w + bb.w, 0.f);
  *(float4*)(x2 + (size_t)i4 * 4) = r;
}

// --------------------------- 1x1 heads GEMM --------------------------------
// logits[m][0..63] = x2[m][:] @ Wco + bco   (grid 40)
__global__ __launch_bounds__(256) void gemm1x1(const float* __restrict__ x2,
                                               const float* __restrict__ Wco,
                                               const float* __restrict__ bco,
                                               float* __restrict__ logits) {
  __shared__ __align__(16) float At[32][68];
  __shared__ __align__(16) float Bt[32][64];
  int tid = threadIdx.x;
  int m0 = blockIdx.x << 6;
  int ti = tid >> 4, tj = tid & 15;
  int si = tid >> 2, sq = tid & 3;
  int skk = tid >> 3, sr = tid & 7;
  float acc[4][4] = {{0.f}};
  int m = m0 + si;
  bool mv = m < NM;
  const float* arow = x2 + (((size_t)(mv ? m : 0)) << 9);
  for (int c0 = 0; c0 < CIN; c0 += 32) {
    __syncthreads();
    float4 a0 = make_float4(0.f, 0.f, 0.f, 0.f), a1 = a0;
    if (mv) {
      a0 = *(const float4*)(arow + c0 + (sq << 2));
      a1 = *(const float4*)(arow + c0 + 16 + (sq << 2));
    }
    int kb = sq << 2;
    At[kb + 0][si] = a0.x; At[kb + 1][si] = a0.y; At[kb + 2][si] = a0.z; At[kb + 3][si] = a0.w;
    At[kb + 16][si] = a1.x; At[kb + 17][si] = a1.y; At[kb + 18][si] = a1.z; At[kb + 19][si] = a1.w;
    const float* bp = Wco + (size_t)(c0 + skk) * 64;
    *(float4*)&Bt[skk][sr << 2] = *(const float4*)(bp + (sr << 2));
    *(float4*)&Bt[skk][32 + (sr << 2)] = *(const float4*)(bp + 32 + (sr << 2));
    __syncthreads();
#pragma unroll
    for (int kk = 0; kk < 32; kk++) {
      float4 avv = *(const float4*)&At[kk][ti << 2];
      float4 bvv = *(const float4*)&Bt[kk][tj << 2];
      float a_[4] = {avv.x, avv.y, avv.z, avv.w};
      float b_[4] = {bvv.x, bvv.y, bvv.z, bvv.w};
#pragma unroll
      for (int u = 0; u < 4; u++)
#pragma unroll
        for (int v = 0; v < 4; v++) acc[u][v] += a_[u] * b_[v];
    }
  }
  float4 bias = *(const float4*)(bco + (tj << 2));
#pragma unroll
  for (int u = 0; u < 4; u++) {
    int mr = m0 + (ti << 2) + u;
    if (mr < NM) {
      float4 r = make_float4(acc[u][0] + bias.x, acc[u][1] + bias.y, acc[u][2] + bias.z,
                             acc[u][3] + bias.w);
      *(float4*)(logits + (size_t)mr * 64 + (tj << 2)) = r;
    }
  }
}

// --------------------------- scores + proposals ----------------------------
__global__ __launch_bounds__(256) void score_box_kernel(const float* __restrict__ logits,
                                                        const int* __restrict__ ih,
                                                        const int* __restrict__ iw,
                                                        BaseAnchors ba,
                                                        float* __restrict__ scores,
                                                        float* __restrict__ props) {
#pragma clang fp contract(off)
  int n = blockIdx.x * 256 + threadIdx.x;
  if (n >= NBATCH * NANCH) return;
  int b = n / NANCH;
  int r = n % NANCH;
  int pos = r / 9, aa = r % 9;
  int py = pos / HWDIM, px = pos % HWDIM;
  const float* L = logits + (size_t)(b * NPOS + pos) * 64;
  float l0 = L[2 * aa], l1 = L[2 * aa + 1];
  float mx = fmaxf(l0, l1);
  float e0 = expf(l0 - mx), e1 = expf(l1 - mx);
  float s = e1 / (e0 + e1);
  float d0 = L[18 + 4 * aa + 0], d1 = L[18 + 4 * aa + 1];
  float d2 = L[18 + 4 * aa + 2], d3 = L[18 + 4 * aa + 3];
  float xf = (float)px * 32.f, yf = (float)py * 32.f;
  float ax1 = ba.x1[aa] + xf, ay1 = ba.y1[aa] + yf;
  float ax2 = ba.x2[aa] + xf, ay2 = ba.y2[aa] + yf;
  float wA = ax2 - ax1, hA = ay2 - ay1;
  float cx = ax1 + 0.5f * wA, cy = ay1 + 0.5f * hA;
  float pcx = d0 * wA + cx, pcy = d1 * hA + cy;
  float pw = expf(d2) * wA, ph = expf(d3) * hA;
  float x1 = pcx - 0.5f * pw, y1 = pcy - 0.5f * ph;
  float x2 = pcx + 0.5f * pw, y2 = pcy + 0.5f * ph;
  float W = (float)iw[0], H = (float)ih[0];
  x1 = fminf(fmaxf(x1, 0.f), W);
  y1 = fminf(fmaxf(y1, 0.f), H);
  x2 = fminf(fmaxf(x2, 0.f), W);
  y2 = fminf(fmaxf(y2, 0.f), H);
  scores[n] = s;
  *(float4*)(props + (size_t)n * 4) = make_float4(x1, y1, x2, y2);
}

// --------------------------- sort (bitonic, stable ties) -------------------
__global__ __launch_bounds__(1024) void sort_kernel(const float* __restrict__ scores,
                                                    const float* __restrict__ props,
                                                    int* __restrict__ order,
                                                    float* __restrict__ sb) {
  __shared__ u64 keys[8192];
  int b = blockIdx.x, tid = threadIdx.x;
  const float* sc = scores + (size_t)b * NANCH;
  for (int i = tid; i < 8192; i += 1024) {
    u64 k = 0ull;
    if (i < NANCH) {
      unsigned int sbits = __float_as_uint(sc[i]);  // scores > 0 -> order-preserving bits
      k = (((u64)sbits) << 32) | (u64)(~(unsigned int)i);
    }
    keys[i] = k;
  }
  __syncthreads();
  for (int k = 2; k <= 8192; k <<= 1) {
    for (int j = k >> 1; j > 0; j >>= 1) {
#pragma unroll
      for (int s = 0; s < 8; s++) {
        int i = tid + (s << 10);
        int p = i ^ j;
        if (p > i) {
          u64 a = keys[i], c = keys[p];
          bool up = ((i & k) == 0);
          bool sw = up ? (a < c) : (a > c);  // descending overall
          if (sw) { keys[i] = c; keys[p] = a; }
        }
      }
      __syncthreads();
    }
  }
  for (int i = tid; i < NANCH; i += 1024) {
    u64 kk = keys[i];
    int orig = (int)(~(unsigned int)kk);
    order[b * NANCH + i] = orig;
    float4 p = *(const float4*)(props + ((size_t)b * NANCH + orig) * 4);
    *(float4*)(sb + ((size_t)b * NANCH + i) * 4) = p;
  }
}

// --------------------------- NMS bitmask (SPARSE lists) --------------------
// Off-diagonal nonzero words appended to lists[b][cb]: (bitsLo, bitsHi, row).
// Append order nondeterministic (atomics) but consumption is a masked OR ->
// result deterministic. Diagonal blocks stored dense in maskd[b][s][lane].
__global__ __launch_bounds__(64) void nms_mask_kernel(const float* __restrict__ sb,
                                                      uint4* __restrict__ lists,
                                                      u32* __restrict__ cnt,
                                                      u64* __restrict__ maskd) {
#pragma clang fp contract(off)
  int rb = blockIdx.x, cb = blockIdx.y, b = blockIdx.z;
  if (cb < rb) return;
  int lane = threadIdx.x;
  __shared__ float4 cbox[64];
  int j0 = cb << 6;
  const float* sbb = sb + (size_t)b * NANCH * 4;
  if (j0 + lane < NANCH) cbox[lane] = *(const float4*)(sbb + (size_t)(j0 + lane) * 4);
  __syncthreads();
  int i = (rb << 6) + lane;
  if (i >= NANCH) return;
  float4 rbox = *(const float4*)(sbb + (size_t)i * 4);
  float rarea = (rbox.z - rbox.x) * (rbox.w - rbox.y);
  u64 bits = 0ull;
  int jmax = NANCH - j0;
  if (jmax > 64) jmax = 64;
  for (int l = 0; l < jmax; l++) {
    int j = j0 + l;
    if (j > i) {
      float4 c = cbox[l];
      float carea = (c.z - c.x) * (c.w - c.y);
      float ltx = fmaxf(rbox.x, c.x), lty = fmaxf(rbox.y, c.y);
      float rbx = fminf(rbox.z, c.z), rby = fminf(rbox.w, c.w);
      float wx = fmaxf(rbx - ltx, 0.f);
      float wy = fmaxf(rby - lty, 0.f);
      float inter = wx * wy;
      float iou = inter / (rarea + carea - inter);  // 0/0 -> NaN -> compare false
      if (iou > 0.7f) bits |= (1ull << l);
    }
  }
  if (rb == cb) {
    maskd[((size_t)b * NW + rb) * 64 + lane] = bits;
  } else if (bits) {
    u32 idx = atomicAdd(&cnt[b * NW + cb], 1u);
    if (idx < CAP)
      lists[((size_t)(b * NW + cb)) * CAP + idx] =
          make_uint4((u32)bits, (u32)(bits >> 32), (u32)i, 0u);
  }
}

// --------------------------- NMS scan (sparse, 1 wave, no barriers) --------
__global__ __launch_bounds__(64, 1) void nms_scan_kernel(const uint4* __restrict__ lists,
                                                         const u32* __restrict__ cnt,
                                                         const u64* __restrict__ maskd,
                                                         const int* __restrict__ order,
                                                         const float* __restrict__ sb,
                                                         float* __restrict__ out) {
  int b = blockIdx.x;
  int lane = threadIdx.x;
  __shared__ u64 keep_sh[NW];
  const u64* md = maskd + (size_t)b * NW * 64;
  const uint4* lb = lists + (size_t)b * NW * CAP;

  // counts into registers: lane l holds cnt[l] and cnt[l+64]
  u32 c0 = (lane < NW) ? cnt[b * NW + lane] : 0u;
  u32 c1 = (lane + 64 < NW) ? cnt[b * NW + lane + 64] : 0u;

  u64 diag = md[lane];  // stripe 0 diagonal (coalesced)
  for (int s = 0; s < NW; s++) {
    u64 Mw = diag;
    if (s + 1 < NW) diag = md[((s + 1) << 6) + lane];  // loop-carried prefetch

    int cn = (int)(u32)__builtin_amdgcn_readlane(
        (int)((s < 64) ? c0 : c1), (s < 64) ? s : s - 64);
    if (cn > CAP) cn = CAP;

    // gather: OR keep-masked list entries
    u64 acc = 0ull;
    for (int p = lane; p < cn; p += 64) {
      uint4 e = lb[(size_t)s * CAP + p];
      u64 kw = keep_sh[e.z >> 6];
      if ((kw >> (e.z & 63)) & 1ull) acc |= (((u64)e.y) << 32) | (u64)e.x;
    }
    u64 cur = waveOr64(acc);

    int nrows = NANCH - (s << 6);
    if (nrows > 64) nrows = 64;
    u64 valid = (nrows < 64) ? ((1ull << nrows) - 1ull) : ~0ull;

    // chain over rows with nonzero out-edges only
    u64 nz = __ballot(Mw != 0ull);
    u64 todo = nz & ~cur & valid;
    while (todo) {
      int t = (int)__builtin_ctzll(todo);
      cur |= bcast64(Mw, t);
      todo &= ~cur;
      todo &= ~(1ull << t);
    }
    u64 alive = (~cur) & valid;
    if (lane == 0) keep_sh[s] = alive;  // same-wave LDS, no barrier needed
  }

  // write output: out[b][orig] = kept ? sorted_box : 0
  for (int i = lane; i < NANCH; i += 64) {
    u64 kw = keep_sh[i >> 6];
    bool kept = ((kw >> (i & 63)) & 1ull) != 0ull;
    int orig = order[b * NANCH + i];
    float4 p = *(const float4*)(sb + ((size_t)b * NANCH + i) * 4);
    float4 o = kept ? p : make_float4(0.f, 0.f, 0.f, 0.f);
    *(float4*)(out + ((size_t)b * NANCH + orig) * 4) = o;
  }
}

// --------------------------- host launcher ---------------------------------

extern "C" void kernel_launch(void* const* d_in, const int* in_sizes, int n_in,
                              void* d_out, int out_size, void* d_ws, size_t ws_size,
                              hipStream_t stream) {
  const float* features = (const float*)d_in[0];
  const float* conv_w   = (const float*)d_in[1];
  const float* conv_b   = (const float*)d_in[2];
  const float* cls_w    = (const float*)d_in[3];
  const float* cls_b    = (const float*)d_in[4];
  const float* bbox_w   = (const float*)d_in[5];
  const float* bbox_b   = (const float*)d_in[6];
  const int*   img_h    = (const int*)d_in[7];
  const int*   img_w    = (const int*)d_in[8];
  float* out = (float*)d_out;
  char* ws = (char*)d_ws;

  // workspace layout (bytes); NMS arrays alias FM/WT/XP (dead by NMS time)
  const size_t OFF_FM    = 0;                  // 5,120,000
  const size_t OFF_WT    = 5120000;            // 9,437,184
  const size_t OFF_XP    = 14557184;           // 15,360,000 (ends 29,917,184)
  const size_t OFF_LISTS = 0;                  // 23,068,672 (4*88*4096*16)
  const size_t OFF_CNT   = 23068672;           // 1,408 -> pad to 23,070,208
  const size_t OFF_MASKD = 23070208;           // 180,224 (ends 23,250,432)
  const size_t OFF_X2  = 29917184;             // 5,120,000
  const size_t OFF_WCO = 35037184;             // 131,072
  const size_t OFF_BCO = 35168256;             // 256
  const size_t OFF_LOG = 35168512;             // 640,000
  const size_t OFF_SC  = 35808512;             // 90,000
  const size_t OFF_PR  = 35898512;             // 360,000
  const size_t OFF_ORD = 36258512;             // 90,000
  const size_t OFF_SB  = 36348512;             // 360,000
  const size_t WS_NEEDED = 36708512;
  if (ws_size < WS_NEEDED) return;

  float* fm   = (float*)(ws + OFF_FM);
  float* Wt   = (float*)(ws + OFF_WT);
  float* xp   = (float*)(ws + OFF_XP);
  uint4* lists = (uint4*)(ws + OFF_LISTS);
  u32*   cnt   = (u32*)(ws + OFF_CNT);
  u64*   maskd = (u64*)(ws + OFF_MASKD);
  float* x2   = (float*)(ws + OFF_X2);
  float* Wco  = (float*)(ws + OFF_WCO);
  float* bco  = (float*)(ws + OFF_BCO);
  float* logits = (float*)(ws + OFF_LOG);
  float* scores = (float*)(ws + OFF_SC);
  float* props  = (float*)(ws + OFF_PR);
  int*   order  = (int*)(ws + OFF_ORD);
  float* sb     = (float*)(ws + OFF_SB);

  // base anchors in double, rounded to f32 exactly like numpy
  BaseAnchors ba;
  {
    const double scales[3] = {64.0, 128.0, 256.0};
    const double ratios[3] = {0.5, 1.0, 2.0};
    int a = 0;
    for (int si = 0; si < 3; si++)
      for (int ri = 0; ri < 3; ri++, a++) {
        double w = scales[si] * sqrt(ratios[ri]);
        double h = scales[si] / sqrt(ratios[ri]);
        ba.x1[a] = (float)(-w / 2.0);
        ba.y1[a] = (float)(-h / 2.0);
        ba.x2[a] = (float)(w / 2.0);
        ba.y2[a] = (float)(h / 2.0);
      }
  }

  transpose_features<<<dim3(20, 16, 4), dim3(32, 8), 0, stream>>>(features, fm);
  transpose_weights<<<dim3(16, 16), 256, 0, stream>>>(conv_w, Wt);
  build_wco<<<128, 256, 0, stream>>>(cls_w, cls_b, bbox_w, bbox_b, Wco, bco);
  conv_gemm<<<dim3(40, 8, 3), 256, 0, stream>>>(fm, Wt, xp);
  combine_relu<<<1250, 256, 0, stream>>>(xp, conv_b, x2);
  gemm1x1<<<40, 256, 0, stream>>>(x2, Wco, bco, logits);
  score_box_kernel<<<88, 256, 0, stream>>>(logits, img_h, img_w, ba, scores, props);
  sort_kernel<<<4, 1024, 0, stream>>>(scores, props, order, sb);
  zero_cnt<<<6, 64, 0, stream>>>(cnt);
  nms_mask_kernel<<<dim3(NW, NW, 4), 64, 0, stream>>>(sb, lists, cnt, maskd);
  nms_scan_kernel<<<4, 64, 0, stream>>>(lists, cnt, maskd, order, sb, out);
}

// Round 11
// 459.745 us; speedup vs baseline: 1.2611x; 1.2611x over previous
//
#include <hip/hip_runtime.h>

// ---------------------------------------------------------------------------
// RPN forward: conv3x3(512->512)+relu, 1x1 heads (18 cls, 36 bbox),
// anchor decode + clip, softmax score, greedy NMS (0.7), keep-masked boxes.
// All decision math in fp32 with contraction OFF to track the numpy reference.
// R11: conv_gemm reverted BYTE-EXACT to R8's 64x64/4x4 (181us best; R9's
//   8x4 tile hit 4-way A-write bank conflicts 216us; R10's dbuf hit VGPR
//   152/occ 11% via runtime-indexed lambda arrays, 295us). nms_scan: list
//   entries for stripe s+1 prefetched into registers during stripe s
//   (addresses independent of keep-state; rows in lists are always < s*64
//   so keep_sh is ready) -> removes the dependent L2 latency per stripe.
// ---------------------------------------------------------------------------

#define NBATCH 4
#define HWDIM  25
#define NPOS   625            // 25*25
#define NM     2500           // NBATCH*NPOS
#define CIN    512
#define NANCH  5625           // NPOS*9
#define NW     88             // ceil(NANCH/64)
#define CAP    4096           // list capacity per (b, colword)

typedef unsigned long long u64;
typedef unsigned int u32;

struct BaseAnchors { float x1[9], y1[9], x2[9], y2[9]; };

__device__ __forceinline__ u64 bcast64(u64 v, int lane) {
  unsigned int lo = (unsigned int)v;
  unsigned int hi = (unsigned int)(v >> 32);
  lo = (unsigned int)__builtin_amdgcn_readlane((int)lo, lane);
  hi = (unsigned int)__builtin_amdgcn_readlane((int)hi, lane);
  return (((u64)hi) << 32) | (u64)lo;
}

__device__ __forceinline__ u64 waveOr64(u64 x) {
  unsigned int lo = (unsigned int)x, hi = (unsigned int)(x >> 32);
#pragma unroll
  for (int off = 32; off > 0; off >>= 1) {
    lo |= (unsigned int)__shfl_xor((int)lo, off, 64);
    hi |= (unsigned int)__shfl_xor((int)hi, off, 64);
  }
  return (((u64)hi) << 32) | (u64)lo;
}

// --------------------------- prep: transposes ------------------------------

// f[b][c][pos] -> fm[b*625+pos][c]
__global__ void transpose_features(const float* __restrict__ f, float* __restrict__ fm) {
  __shared__ float tile[32][33];
  int b  = blockIdx.z;
  int p0 = blockIdx.x * 32;
  int c0 = blockIdx.y * 32;
  int tx = threadIdx.x, ty = threadIdx.y;  // (32, 8)
#pragma unroll
  for (int j = 0; j < 4; j++) {
    int c = c0 + ty + j * 8;
    int p = p0 + tx;
    if (p < NPOS) tile[ty + j * 8][tx] = f[((size_t)(b * CIN + c)) * NPOS + p];
  }
  __syncthreads();
#pragma unroll
  for (int j = 0; j < 4; j++) {
    int p = p0 + ty + j * 8;
    int c = c0 + tx;
    if (p < NPOS) fm[((size_t)(b * NPOS + p)) * CIN + c] = tile[tx][ty + j * 8];
  }
}

// conv_w[o][c][tap] -> Wt[tap][c][o]
__global__ __launch_bounds__(256) void transpose_weights(const float* __restrict__ cw,
                                                         float* __restrict__ Wt) {
  __shared__ float tile[32][289];
  int o0 = blockIdx.x * 32, c0 = blockIdx.y * 32;
  int tid = threadIdx.x;
#pragma unroll
  for (int j = 0; j < 36; j++) {
    int idx = tid + j * 256;            // 0..9215
    int o = idx / 288, kk = idx % 288;  // kk = c_rel*9 + tap
    tile[o][kk] = cw[((size_t)(o0 + o)) * 4608 + c0 * 9 + kk];
  }
  __syncthreads();
  int ol = tid & 31, pg = tid >> 5;  // 0..7
#pragma unroll
  for (int j = 0; j < 36; j++) {
    int pair = pg + j * 8;  // 0..287 == c_rel*9 + tap
    int c = pair / 9, tap = pair % 9;
    Wt[((size_t)tap * CIN + (c0 + c)) * 512 + o0 + ol] = tile[ol][pair];
  }
}

// combined 1x1 head weights: Wco[c][o] (o: 0..17 cls, 18..53 bbox, 54..63 zero)
__global__ void build_wco(const float* __restrict__ clsw, const float* __restrict__ clsb,
                          const float* __restrict__ bw, const float* __restrict__ bbb,
                          float* __restrict__ Wco, float* __restrict__ bco) {
  int idx = blockIdx.x * 256 + threadIdx.x;
  if (idx < 512 * 64) {
    int c = idx >> 6, o = idx & 63;
    float v = 0.f;
    if (o < 18) v = clsw[o * 512 + c];
    else if (o < 54) v = bw[(o - 18) * 512 + c];
    Wco[idx] = v;
  }
  if (idx < 64) {
    float v = 0.f;
    if (idx < 18) v = clsb[idx];
    else if (idx < 54) v = bbb[idx - 18];
    bco[idx] = v;
  }
}

__global__ void zero_cnt(u32* __restrict__ cnt) {
  int i = blockIdx.x * 64 + threadIdx.x;
  if (i < NBATCH * NW) cnt[i] = 0u;
}

// --------------------------- conv3x3 implicit GEMM -------------------------
// grid (40, 8, 3): 64 m-rows x 64 o-cols per block, part = 3 taps (dy fixed).
// Writes partial sums (no bias/relu) to xp[part][m][o].  [R8 version, 181us]
__global__ __launch_bounds__(256) void conv_gemm(const float* __restrict__ fm,
                                                 const float* __restrict__ Wt,
                                                 float* __restrict__ xp) {
  __shared__ __align__(16) float At[32][68];
  __shared__ __align__(16) float Bt[32][64];
  int tid = threadIdx.x;
  int m0 = blockIdx.x << 6;
  int o0 = blockIdx.y << 6;
  int part = blockIdx.z;  // 0..2 -> dy = part-1
  int ti = tid >> 4, tj = tid & 15;   // compute tile 4x4
  int si = tid >> 2, sq = tid & 3;    // A staging: row si, col quad sq
  int skk = tid >> 3, sr = tid & 7;   // B staging: k-row skk, col oct sr
  float acc[4][4] = {{0.f}};

  int m = m0 + si;
  bool mv = m < NM;
  int mm = mv ? m : 0;
  int bb = mm / NPOS, rem = mm % NPOS;
  int hh = rem / HWDIM, ww = rem % HWDIM;
  int dy = part - 1;

  for (int tt = 0; tt < 3; tt++) {
    int tap = part * 3 + tt;
    int dx = tt - 1;
    int h2 = hh + dy, w2 = ww + dx;
    bool av = mv && ((unsigned)h2 < (unsigned)HWDIM) && ((unsigned)w2 < (unsigned)HWDIM);
    const float* arow = fm + (((size_t)(bb * NPOS + h2 * HWDIM + w2)) << 9);
    const float* bbase = Wt + (((size_t)tap) << 18) + o0;
    for (int c0 = 0; c0 < CIN; c0 += 32) {
      __syncthreads();
      float4 a0 = make_float4(0.f, 0.f, 0.f, 0.f), a1 = a0;
      if (av) {
        a0 = *(const float4*)(arow + c0 + (sq << 2));
        a1 = *(const float4*)(arow + c0 + 16 + (sq << 2));
      }
      int kb = sq << 2;
      At[kb + 0][si] = a0.x; At[kb + 1][si] = a0.y; At[kb + 2][si] = a0.z; At[kb + 3][si] = a0.w;
      At[kb + 16][si] = a1.x; At[kb + 17][si] = a1.y; At[kb + 18][si] = a1.z; At[kb + 19][si] = a1.w;
      const float* bp = bbase + (((size_t)(c0 + skk)) << 9);
      *(float4*)&Bt[skk][sr << 2] = *(const float4*)(bp + (sr << 2));
      *(float4*)&Bt[skk][32 + (sr << 2)] = *(const float4*)(bp + 32 + (sr << 2));
      __syncthreads();
#pragma unroll
      for (int kk = 0; kk < 32; kk++) {
        float4 avv = *(const float4*)&At[kk][ti << 2];
        float4 bvv = *(const float4*)&Bt[kk][tj << 2];
        float a_[4] = {avv.x, avv.y, avv.z, avv.w};
        float b_[4] = {bvv.x, bvv.y, bvv.z, bvv.w};
#pragma unroll
        for (int u = 0; u < 4; u++)
#pragma unroll
          for (int v = 0; v < 4; v++) acc[u][v] += a_[u] * b_[v];
      }
    }
  }
  float* outp = xp + (size_t)part * (NM * 512);
#pragma unroll
  for (int u = 0; u < 4; u++) {
    int mr = m0 + (ti << 2) + u;
    if (mr < NM) {
      float4 r = make_float4(acc[u][0], acc[u][1], acc[u][2], acc[u][3]);
      *(float4*)(outp + (((size_t)mr) << 9) + o0 + (tj << 2)) = r;
    }
  }
}

// x2 = relu(xp0+xp1+xp2+bias)
__global__ void combine_relu(const float* __restrict__ xp, const float* __restrict__ bias,
                             float* __restrict__ x2) {
  int i4 = blockIdx.x * 256 + threadIdx.x;  // over 320000 float4s
  if (i4 >= NM * 128) return;
  float4 p0 = *(const float4*)(xp + (size_t)i4 * 4);
  float4 p1 = *(const float4*)(xp + (size_t)(NM * 512) + (size_t)i4 * 4);
  float4 p2 = *(const float4*)(xp + (size_t)(2 * NM * 512) + (size_t)i4 * 4);
  float4 bb = *(const float4*)(bias + (i4 & 127) * 4);
  float4 r;
  r.x = fmaxf(p0.x + p1.x + p2.x + bb.x, 0.f);
  r.y = fmaxf(p0.y + p1.y + p2.y + bb.y, 0.f);
  r.z = fmaxf(p0.z + p1.z + p2.z + bb.z, 0.f);
  r.w = fmaxf(p0.w + p1.w + p2.w + bb.w, 0.f);
  *(float4*)(x2 + (size_t)i4 * 4) = r;
}

// --------------------------- 1x1 heads GEMM --------------------------------
// logits[m][0..63] = x2[m][:] @ Wco + bco   (grid 40)
__global__ __launch_bounds__(256) void gemm1x1(const float* __restrict__ x2,
                                               const float* __restrict__ Wco,
                                               const float* __restrict__ bco,
                                               float* __restrict__ logits) {
  __shared__ __align__(16) float At[32][68];
  __shared__ __align__(16) float Bt[32][64];
  int tid = threadIdx.x;
  int m0 = blockIdx.x << 6;
  int ti = tid >> 4, tj = tid & 15;
  int si = tid >> 2, sq = tid & 3;
  int skk = tid >> 3, sr = tid & 7;
  float acc[4][4] = {{0.f}};
  int m = m0 + si;
  bool mv = m < NM;
  const float* arow = x2 + (((size_t)(mv ? m : 0)) << 9);
  for (int c0 = 0; c0 < CIN; c0 += 32) {
    __syncthreads();
    float4 a0 = make_float4(0.f, 0.f, 0.f, 0.f), a1 = a0;
    if (mv) {
      a0 = *(const float4*)(arow + c0 + (sq << 2));
      a1 = *(const float4*)(arow + c0 + 16 + (sq << 2));
    }
    int kb = sq << 2;
    At[kb + 0][si] = a0.x; At[kb + 1][si] = a0.y; At[kb + 2][si] = a0.z; At[kb + 3][si] = a0.w;
    At[kb + 16][si] = a1.x; At[kb + 17][si] = a1.y; At[kb + 18][si] = a1.z; At[kb + 19][si] = a1.w;
    const float* bp = Wco + (size_t)(c0 + skk) * 64;
    *(float4*)&Bt[skk][sr << 2] = *(const float4*)(bp + (sr << 2));
    *(float4*)&Bt[skk][32 + (sr << 2)] = *(const float4*)(bp + 32 + (sr << 2));
    __syncthreads();
#pragma unroll
    for (int kk = 0; kk < 32; kk++) {
      float4 avv = *(const float4*)&At[kk][ti << 2];
      float4 bvv = *(const float4*)&Bt[kk][tj << 2];
      float a_[4] = {avv.x, avv.y, avv.z, avv.w};
      float b_[4] = {bvv.x, bvv.y, bvv.z, bvv.w};
#pragma unroll
      for (int u = 0; u < 4; u++)
#pragma unroll
        for (int v = 0; v < 4; v++) acc[u][v] += a_[u] * b_[v];
    }
  }
  float4 bias = *(const float4*)(bco + (tj << 2));
#pragma unroll
  for (int u = 0; u < 4; u++) {
    int mr = m0 + (ti << 2) + u;
    if (mr < NM) {
      float4 r = make_float4(acc[u][0] + bias.x, acc[u][1] + bias.y, acc[u][2] + bias.z,
                             acc[u][3] + bias.w);
      *(float4*)(logits + (size_t)mr * 64 + (tj << 2)) = r;
    }
  }
}

// --------------------------- scores + proposals ----------------------------
__global__ __launch_bounds__(256) void score_box_kernel(const float* __restrict__ logits,
                                                        const int* __restrict__ ih,
                                                        const int* __restrict__ iw,
                                                        BaseAnchors ba,
                                                        float* __restrict__ scores,
                                                        float* __restrict__ props) {
#pragma clang fp contract(off)
  int n = blockIdx.x * 256 + threadIdx.x;
  if (n >= NBATCH * NANCH) return;
  int b = n / NANCH;
  int r = n % NANCH;
  int pos = r / 9, aa = r % 9;
  int py = pos / HWDIM, px = pos % HWDIM;
  const float* L = logits + (size_t)(b * NPOS + pos) * 64;
  float l0 = L[2 * aa], l1 = L[2 * aa + 1];
  float mx = fmaxf(l0, l1);
  float e0 = expf(l0 - mx), e1 = expf(l1 - mx);
  float s = e1 / (e0 + e1);
  float d0 = L[18 + 4 * aa + 0], d1 = L[18 + 4 * aa + 1];
  float d2 = L[18 + 4 * aa + 2], d3 = L[18 + 4 * aa + 3];
  float xf = (float)px * 32.f, yf = (float)py * 32.f;
  float ax1 = ba.x1[aa] + xf, ay1 = ba.y1[aa] + yf;
  float ax2 = ba.x2[aa] + xf, ay2 = ba.y2[aa] + yf;
  float wA = ax2 - ax1, hA = ay2 - ay1;
  float cx = ax1 + 0.5f * wA, cy = ay1 + 0.5f * hA;
  float pcx = d0 * wA + cx, pcy = d1 * hA + cy;
  float pw = expf(d2) * wA, ph = expf(d3) * hA;
  float x1 = pcx - 0.5f * pw, y1 = pcy - 0.5f * ph;
  float x2 = pcx + 0.5f * pw, y2 = pcy + 0.5f * ph;
  float W = (float)iw[0], H = (float)ih[0];
  x1 = fminf(fmaxf(x1, 0.f), W);
  y1 = fminf(fmaxf(y1, 0.f), H);
  x2 = fminf(fmaxf(x2, 0.f), W);
  y2 = fminf(fmaxf(y2, 0.f), H);
  scores[n] = s;
  *(float4*)(props + (size_t)n * 4) = make_float4(x1, y1, x2, y2);
}

// --------------------------- sort (bitonic, stable ties) -------------------
__global__ __launch_bounds__(1024) void sort_kernel(const float* __restrict__ scores,
                                                    const float* __restrict__ props,
                                                    int* __restrict__ order,
                                                    float* __restrict__ sb) {
  __shared__ u64 keys[8192];
  int b = blockIdx.x, tid = threadIdx.x;
  const float* sc = scores + (size_t)b * NANCH;
  for (int i = tid; i < 8192; i += 1024) {
    u64 k = 0ull;
    if (i < NANCH) {
      unsigned int sbits = __float_as_uint(sc[i]);  // scores > 0 -> order-preserving bits
      k = (((u64)sbits) << 32) | (u64)(~(unsigned int)i);
    }
    keys[i] = k;
  }
  __syncthreads();
  for (int k = 2; k <= 8192; k <<= 1) {
    for (int j = k >> 1; j > 0; j >>= 1) {
#pragma unroll
      for (int s = 0; s < 8; s++) {
        int i = tid + (s << 10);
        int p = i ^ j;
        if (p > i) {
          u64 a = keys[i], c = keys[p];
          bool up = ((i & k) == 0);
          bool sw = up ? (a < c) : (a > c);  // descending overall
          if (sw) { keys[i] = c; keys[p] = a; }
        }
      }
      __syncthreads();
    }
  }
  for (int i = tid; i < NANCH; i += 1024) {
    u64 kk = keys[i];
    int orig = (int)(~(unsigned int)kk);
    order[b * NANCH + i] = orig;
    float4 p = *(const float4*)(props + ((size_t)b * NANCH + orig) * 4);
    *(float4*)(sb + ((size_t)b * NANCH + i) * 4) = p;
  }
}

// --------------------------- NMS bitmask (SPARSE lists) --------------------
// Off-diagonal nonzero words appended to lists[b][cb]: (bitsLo, bitsHi, row).
// Append order nondeterministic (atomics) but consumption is a masked OR ->
// result deterministic. Diagonal blocks stored dense in maskd[b][s][lane].
__global__ __launch_bounds__(64) void nms_mask_kernel(const float* __restrict__ sb,
                                                      uint4* __restrict__ lists,
                                                      u32* __restrict__ cnt,
                                                      u64* __restrict__ maskd) {
#pragma clang fp contract(off)
  int rb = blockIdx.x, cb = blockIdx.y, b = blockIdx.z;
  if (cb < rb) return;
  int lane = threadIdx.x;
  __shared__ float4 cbox[64];
  int j0 = cb << 6;
  const float* sbb = sb + (size_t)b * NANCH * 4;
  if (j0 + lane < NANCH) cbox[lane] = *(const float4*)(sbb + (size_t)(j0 + lane) * 4);
  __syncthreads();
  int i = (rb << 6) + lane;
  if (i >= NANCH) return;
  float4 rbox = *(const float4*)(sbb + (size_t)i * 4);
  float rarea = (rbox.z - rbox.x) * (rbox.w - rbox.y);
  u64 bits = 0ull;
  int jmax = NANCH - j0;
  if (jmax > 64) jmax = 64;
  for (int l = 0; l < jmax; l++) {
    int j = j0 + l;
    if (j > i) {
      float4 c = cbox[l];
      float carea = (c.z - c.x) * (c.w - c.y);
      float ltx = fmaxf(rbox.x, c.x), lty = fmaxf(rbox.y, c.y);
      float rbx = fminf(rbox.z, c.z), rby = fminf(rbox.w, c.w);
      float wx = fmaxf(rbx - ltx, 0.f);
      float wy = fmaxf(rby - lty, 0.f);
      float inter = wx * wy;
      float iou = inter / (rarea + carea - inter);  // 0/0 -> NaN -> compare false
      if (iou > 0.7f) bits |= (1ull << l);
    }
  }
  if (rb == cb) {
    maskd[((size_t)b * NW + rb) * 64 + lane] = bits;
  } else if (bits) {
    u32 idx = atomicAdd(&cnt[b * NW + cb], 1u);
    if (idx < CAP)
      lists[((size_t)(b * NW + cb)) * CAP + idx] =
          make_uint4((u32)bits, (u32)(bits >> 32), (u32)i, 0u);
  }
}

// --------------------------- NMS scan (sparse, 1 wave, no barriers) --------
// Per stripe s: cur = OR over keep-masked list entries; ctz chain over rows
// with nonzero diagonal out-edges. List head (first 64 entries) AND diagonal
// for stripe s+1 prefetched during stripe s (loop-carried registers) -> the
// dependent L2 latency is off the critical path. List rows are always < s*64
// (rb < cb strictly), so keep_sh[e.z>>6] is already written.
__global__ __launch_bounds__(64, 1) void nms_scan_kernel(const uint4* __restrict__ lists,
                                                         const u32* __restrict__ cnt,
                                                         const u64* __restrict__ maskd,
                                                         const int* __restrict__ order,
                                                         const float* __restrict__ sb,
                                                         float* __restrict__ out) {
  int b = blockIdx.x;
  int lane = threadIdx.x;
  __shared__ u64 keep_sh[NW];
  const u64* md = maskd + (size_t)b * NW * 64;
  const uint4* lb = lists + (size_t)b * NW * CAP;

  // counts into registers: lane l holds cnt[l] and cnt[l+64]
  u32 c0 = (lane < NW) ? cnt[b * NW + lane] : 0u;
  u32 c1 = (lane + 64 < NW) ? cnt[b * NW + lane + 64] : 0u;

  u64 diag = md[lane];   // stripe 0 diagonal (coalesced)
  uint4 pf = lb[lane];   // stripe 0 list head prefetch
  for (int s = 0; s < NW; s++) {
    u64 Mw = diag;
    uint4 e0 = pf;
    if (s + 1 < NW) {
      diag = md[((s + 1) << 6) + lane];          // loop-carried prefetch
      pf = lb[(size_t)(s + 1) * CAP + lane];     // next list head in flight
    }

    int cn = (int)(u32)__builtin_amdgcn_readlane(
        (int)((s < 64) ? c0 : c1), (s < 64) ? s : s - 64);
    if (cn > CAP) cn = CAP;

    // gather: OR keep-masked list entries (first 64 from prefetch)
    u64 acc = 0ull;
    if (lane < cn) {
      u64 kw = keep_sh[e0.z >> 6];
      if ((kw >> (e0.z & 63)) & 1ull) acc |= (((u64)e0.y) << 32) | (u64)e0.x;
    }
    for (int p = lane + 64; p < cn; p += 64) {
      uint4 e = lb[(size_t)s * CAP + p];
      u64 kw = keep_sh[e.z >> 6];
      if ((kw >> (e.z & 63)) & 1ull) acc |= (((u64)e.y) << 32) | (u64)e.x;
    }
    u64 cur = waveOr64(acc);

    int nrows = NANCH - (s << 6);
    if (nrows > 64) nrows = 64;
    u64 valid = (nrows < 64) ? ((1ull << nrows) - 1ull) : ~0ull;

    // chain over rows with nonzero out-edges only
    u64 nz = __ballot(Mw != 0ull);
    u64 todo = nz & ~cur & valid;
    while (todo) {
      int t = (int)__builtin_ctzll(todo);
      cur |= bcast64(Mw, t);
      todo &= ~cur;
      todo &= ~(1ull << t);
    }
    u64 alive = (~cur) & valid;
    if (lane == 0) keep_sh[s] = alive;  // same-wave LDS, no barrier needed
  }

  // write output: out[b][orig] = kept ? sorted_box : 0
  for (int i = lane; i < NANCH; i += 64) {
    u64 kw = keep_sh[i >> 6];
    bool kept = ((kw >> (i & 63)) & 1ull) != 0ull;
    int orig = order[b * NANCH + i];
    float4 p = *(const float4*)(sb + ((size_t)b * NANCH + i) * 4);
    float4 o = kept ? p : make_float4(0.f, 0.f, 0.f, 0.f);
    *(float4*)(out + ((size_t)b * NANCH + orig) * 4) = o;
  }
}

// --------------------------- host launcher ---------------------------------

extern "C" void kernel_launch(void* const* d_in, const int* in_sizes, int n_in,
                              void* d_out, int out_size, void* d_ws, size_t ws_size,
                              hipStream_t stream) {
  const float* features = (const float*)d_in[0];
  const float* conv_w   = (const float*)d_in[1];
  const float* conv_b   = (const float*)d_in[2];
  const float* cls_w    = (const float*)d_in[3];
  const float* cls_b    = (const float*)d_in[4];
  const float* bbox_w   = (const float*)d_in[5];
  const float* bbox_b   = (const float*)d_in[6];
  const int*   img_h    = (const int*)d_in[7];
  const int*   img_w    = (const int*)d_in[8];
  float* out = (float*)d_out;
  char* ws = (char*)d_ws;

  // workspace layout (bytes); NMS arrays alias FM/WT/XP (dead by NMS time)
  const size_t OFF_FM    = 0;                  // 5,120,000
  const size_t OFF_WT    = 5120000;            // 9,437,184
  const size_t OFF_XP    = 14557184;           // 15,360,000 (ends 29,917,184)
  const size_t OFF_LISTS = 0;                  // 23,068,672 (4*88*4096*16)
  const size_t OFF_CNT   = 23068672;           // 1,408 -> pad to 23,070,208
  const size_t OFF_MASKD = 23070208;           // 180,224 (ends 23,250,432)
  const size_t OFF_X2  = 29917184;             // 5,120,000
  const size_t OFF_WCO = 35037184;             // 131,072
  const size_t OFF_BCO = 35168256;             // 256
  const size_t OFF_LOG = 35168512;             // 640,000
  const size_t OFF_SC  = 35808512;             // 90,000
  const size_t OFF_PR  = 35898512;             // 360,000
  const size_t OFF_ORD = 36258512;             // 90,000
  const size_t OFF_SB  = 36348512;             // 360,000
  const size_t WS_NEEDED = 36708512;
  if (ws_size < WS_NEEDED) return;

  float* fm   = (float*)(ws + OFF_FM);
  float* Wt   = (float*)(ws + OFF_WT);
  float* xp   = (float*)(ws + OFF_XP);
  uint4* lists = (uint4*)(ws + OFF_LISTS);
  u32*   cnt   = (u32*)(ws + OFF_CNT);
  u64*   maskd = (u64*)(ws + OFF_MASKD);
  float* x2   = (float*)(ws + OFF_X2);
  float* Wco  = (float*)(ws + OFF_WCO);
  float* bco  = (float*)(ws + OFF_BCO);
  float* logits = (float*)(ws + OFF_LOG);
  float* scores = (float*)(ws + OFF_SC);
  float* props  = (float*)(ws + OFF_PR);
  int*   order  = (int*)(ws + OFF_ORD);
  float* sb     = (float*)(ws + OFF_SB);

  // base anchors in double, rounded to f32 exactly like numpy
  BaseAnchors ba;
  {
    const double scales[3] = {64.0, 128.0, 256.0};
    const double ratios[3] = {0.5, 1.0, 2.0};
    int a = 0;
    for (int si = 0; si < 3; si++)
      for (int ri = 0; ri < 3; ri++, a++) {
        double w = scales[si] * sqrt(ratios[ri]);
        double h = scales[si] / sqrt(ratios[ri]);
        ba.x1[a] = (float)(-w / 2.0);
        ba.y1[a] = (float)(-h / 2.0);
        ba.x2[a] = (float)(w / 2.0);
        ba.y2[a] = (float)(h / 2.0);
      }
  }

  transpose_features<<<dim3(20, 16, 4), dim3(32, 8), 0, stream>>>(features, fm);
  transpose_weights<<<dim3(16, 16), 256, 0, stream>>>(conv_w, Wt);
  build_wco<<<128, 256, 0, stream>>>(cls_w, cls_b, bbox_w, bbox_b, Wco, bco);
  conv_gemm<<<dim3(40, 8, 3), 256, 0, stream>>>(fm, Wt, xp);
  combine_relu<<<1250, 256, 0, stream>>>(xp, conv_b, x2);
  gemm1x1<<<40, 256, 0, stream>>>(x2, Wco, bco, logits);
  score_box_kernel<<<88, 256, 0, stream>>>(logits, img_h, img_w, ba, scores, props);
  sort_kernel<<<4, 1024, 0, stream>>>(scores, props, order, sb);
  zero_cnt<<<6, 64, 0, stream>>>(cnt);
  nms_mask_kernel<<<dim3(NW, NW, 4), 64, 0, stream>>>(sb, lists, cnt, maskd);
  nms_scan_kernel<<<4, 64, 0, stream>>>(lists, cnt, maskd, order, sb, out);
}

// Round 12
// 457.465 us; speedup vs baseline: 1.2674x; 1.0050x over previous
//
#include <hip/hip_runtime.h>

// ---------------------------------------------------------------------------
// RPN forward: conv3x3(512->512)+relu, 1x1 heads (18 cls, 36 bbox),
// anchor decode + clip, softmax score, greedy NMS (0.7), keep-masked boxes.
// All decision math in fp32 with contraction OFF to track the numpy reference.
// R12: conv_gemm = R8 tile (64x64/4x4, 181us) + STATIC load/use rotation:
//   barrier -> LDS-write(regs from last iter) -> issue next tile's global
//   loads (named float4 scalars; land during compute) -> barrier -> compute.
//   Same barriers, same FMA order (bitwise-identical output), +16 VGPR.
//   (R10's dbuf failed via lambda/runtime-indexed arrays: VGPR 152, occ 11%.)
//   NMS: R8 sparse lists + R11 prefetched 1-wave scan (kept).
// ---------------------------------------------------------------------------

#define NBATCH 4
#define HWDIM  25
#define NPOS   625            // 25*25
#define NM     2500           // NBATCH*NPOS
#define CIN    512
#define NANCH  5625           // NPOS*9
#define NW     88             // ceil(NANCH/64)
#define CAP    4096           // list capacity per (b, colword)

typedef unsigned long long u64;
typedef unsigned int u32;

struct BaseAnchors { float x1[9], y1[9], x2[9], y2[9]; };

__device__ __forceinline__ u64 bcast64(u64 v, int lane) {
  unsigned int lo = (unsigned int)v;
  unsigned int hi = (unsigned int)(v >> 32);
  lo = (unsigned int)__builtin_amdgcn_readlane((int)lo, lane);
  hi = (unsigned int)__builtin_amdgcn_readlane((int)hi, lane);
  return (((u64)hi) << 32) | (u64)lo;
}

__device__ __forceinline__ u64 waveOr64(u64 x) {
  unsigned int lo = (unsigned int)x, hi = (unsigned int)(x >> 32);
#pragma unroll
  for (int off = 32; off > 0; off >>= 1) {
    lo |= (unsigned int)__shfl_xor((int)lo, off, 64);
    hi |= (unsigned int)__shfl_xor((int)hi, off, 64);
  }
  return (((u64)hi) << 32) | (u64)lo;
}

// --------------------------- prep: transposes ------------------------------

// f[b][c][pos] -> fm[b*625+pos][c]
__global__ void transpose_features(const float* __restrict__ f, float* __restrict__ fm) {
  __shared__ float tile[32][33];
  int b  = blockIdx.z;
  int p0 = blockIdx.x * 32;
  int c0 = blockIdx.y * 32;
  int tx = threadIdx.x, ty = threadIdx.y;  // (32, 8)
#pragma unroll
  for (int j = 0; j < 4; j++) {
    int c = c0 + ty + j * 8;
    int p = p0 + tx;
    if (p < NPOS) tile[ty + j * 8][tx] = f[((size_t)(b * CIN + c)) * NPOS + p];
  }
  __syncthreads();
#pragma unroll
  for (int j = 0; j < 4; j++) {
    int p = p0 + ty + j * 8;
    int c = c0 + tx;
    if (p < NPOS) fm[((size_t)(b * NPOS + p)) * CIN + c] = tile[tx][ty + j * 8];
  }
}

// conv_w[o][c][tap] -> Wt[tap][c][o]
__global__ __launch_bounds__(256) void transpose_weights(const float* __restrict__ cw,
                                                         float* __restrict__ Wt) {
  __shared__ float tile[32][289];
  int o0 = blockIdx.x * 32, c0 = blockIdx.y * 32;
  int tid = threadIdx.x;
#pragma unroll
  for (int j = 0; j < 36; j++) {
    int idx = tid + j * 256;            // 0..9215
    int o = idx / 288, kk = idx % 288;  // kk = c_rel*9 + tap
    tile[o][kk] = cw[((size_t)(o0 + o)) * 4608 + c0 * 9 + kk];
  }
  __syncthreads();
  int ol = tid & 31, pg = tid >> 5;  // 0..7
#pragma unroll
  for (int j = 0; j < 36; j++) {
    int pair = pg + j * 8;  // 0..287 == c_rel*9 + tap
    int c = pair / 9, tap = pair % 9;
    Wt[((size_t)tap * CIN + (c0 + c)) * 512 + o0 + ol] = tile[ol][pair];
  }
}

// combined 1x1 head weights: Wco[c][o] (o: 0..17 cls, 18..53 bbox, 54..63 zero)
__global__ void build_wco(const float* __restrict__ clsw, const float* __restrict__ clsb,
                          const float* __restrict__ bw, const float* __restrict__ bbb,
                          float* __restrict__ Wco, float* __restrict__ bco) {
  int idx = blockIdx.x * 256 + threadIdx.x;
  if (idx < 512 * 64) {
    int c = idx >> 6, o = idx & 63;
    float v = 0.f;
    if (o < 18) v = clsw[o * 512 + c];
    else if (o < 54) v = bw[(o - 18) * 512 + c];
    Wco[idx] = v;
  }
  if (idx < 64) {
    float v = 0.f;
    if (idx < 18) v = clsb[idx];
    else if (idx < 54) v = bbb[idx - 18];
    bco[idx] = v;
  }
}

__global__ void zero_cnt(u32* __restrict__ cnt) {
  int i = blockIdx.x * 64 + threadIdx.x;
  if (i < NBATCH * NW) cnt[i] = 0u;
}

// --------------------------- conv3x3 implicit GEMM -------------------------
// grid (40, 8, 3): 64 m-rows x 64 o-cols per block, part = 3 taps (dy fixed).
// Per c0 iter: barrier -> LDS-write(cur regs) -> issue next loads -> barrier
// -> compute. Next tile's loads ride under the FMA block. FMA order == R8.
__global__ __launch_bounds__(256) void conv_gemm(const float* __restrict__ fm,
                                                 const float* __restrict__ Wt,
                                                 float* __restrict__ xp) {
  __shared__ __align__(16) float At[32][68];
  __shared__ __align__(16) float Bt[32][64];
  int tid = threadIdx.x;
  int m0 = blockIdx.x << 6;
  int o0 = blockIdx.y << 6;
  int part = blockIdx.z;  // 0..2 -> dy = part-1
  int ti = tid >> 4, tj = tid & 15;   // compute tile 4x4
  int si = tid >> 2, sq = tid & 3;    // A staging: row si, col quad sq
  int skk = tid >> 3, sr = tid & 7;   // B staging: k-row skk, col oct sr
  float acc[4][4] = {{0.f}};

  int m = m0 + si;
  bool mv = m < NM;
  int mm = mv ? m : 0;
  int bb = mm / NPOS, rem = mm % NPOS;
  int hh = rem / HWDIM, ww = rem % HWDIM;
  int dy = part - 1;

  for (int tt = 0; tt < 3; tt++) {
    int tap = part * 3 + tt;
    int dx = tt - 1;
    int h2 = hh + dy, w2 = ww + dx;
    bool av = mv && ((unsigned)h2 < (unsigned)HWDIM) && ((unsigned)w2 < (unsigned)HWDIM);
    const float* arow = fm + (((size_t)(bb * NPOS + h2 * HWDIM + w2)) << 9);
    const float* bbase = Wt + (((size_t)tap) << 18) + o0;

    // prologue: load c0=0 tile into registers
    float4 a0 = make_float4(0.f, 0.f, 0.f, 0.f), a1 = a0;
    if (av) {
      a0 = *(const float4*)(arow + (sq << 2));
      a1 = *(const float4*)(arow + 16 + (sq << 2));
    }
    const float* bp0 = bbase + (((size_t)skk) << 9);
    float4 b0 = *(const float4*)(bp0 + (sr << 2));
    float4 b1 = *(const float4*)(bp0 + 32 + (sr << 2));

    for (int c0 = 0; c0 < CIN; c0 += 32) {
      __syncthreads();
      // write current tile (loaded last iteration / prologue)
      int kb = sq << 2;
      At[kb + 0][si] = a0.x; At[kb + 1][si] = a0.y; At[kb + 2][si] = a0.z; At[kb + 3][si] = a0.w;
      At[kb + 16][si] = a1.x; At[kb + 17][si] = a1.y; At[kb + 18][si] = a1.z; At[kb + 19][si] = a1.w;
      *(float4*)&Bt[skk][sr << 2] = b0;
      *(float4*)&Bt[skk][32 + (sr << 2)] = b1;
      // issue next tile's loads (land during compute below)
      float4 na0 = make_float4(0.f, 0.f, 0.f, 0.f), na1 = na0;
      float4 nb0 = na0, nb1 = na0;
      int c1 = c0 + 32;
      if (c1 < CIN) {
        if (av) {
          na0 = *(const float4*)(arow + c1 + (sq << 2));
          na1 = *(const float4*)(arow + c1 + 16 + (sq << 2));
        }
        const float* bp = bbase + (((size_t)(c1 + skk)) << 9);
        nb0 = *(const float4*)(bp + (sr << 2));
        nb1 = *(const float4*)(bp + 32 + (sr << 2));
      }
      __syncthreads();
#pragma unroll
      for (int kk = 0; kk < 32; kk++) {
        float4 avv = *(const float4*)&At[kk][ti << 2];
        float4 bvv = *(const float4*)&Bt[kk][tj << 2];
        float a_[4] = {avv.x, avv.y, avv.z, avv.w};
        float b_[4] = {bvv.x, bvv.y, bvv.z, bvv.w};
#pragma unroll
        for (int u = 0; u < 4; u++)
#pragma unroll
          for (int v = 0; v < 4; v++) acc[u][v] += a_[u] * b_[v];
      }
      a0 = na0; a1 = na1; b0 = nb0; b1 = nb1;
    }
  }
  float* outp = xp + (size_t)part * (NM * 512);
#pragma unroll
  for (int u = 0; u < 4; u++) {
    int mr = m0 + (ti << 2) + u;
    if (mr < NM) {
      float4 r = make_float4(acc[u][0], acc[u][1], acc[u][2], acc[u][3]);
      *(float4*)(outp + (((size_t)mr) << 9) + o0 + (tj << 2)) = r;
    }
  }
}

// x2 = relu(xp0+xp1+xp2+bias)
__global__ void combine_relu(const float* __restrict__ xp, const float* __restrict__ bias,
                             float* __restrict__ x2) {
  int i4 = blockIdx.x * 256 + threadIdx.x;  // over 320000 float4s
  if (i4 >= NM * 128) return;
  float4 p0 = *(const float4*)(xp + (size_t)i4 * 4);
  float4 p1 = *(const float4*)(xp + (size_t)(NM * 512) + (size_t)i4 * 4);
  float4 p2 = *(const float4*)(xp + (size_t)(2 * NM * 512) + (size_t)i4 * 4);
  float4 bb = *(const float4*)(bias + (i4 & 127) * 4);
  float4 r;
  r.x = fmaxf(p0.x + p1.x + p2.x + bb.x, 0.f);
  r.y = fmaxf(p0.y + p1.y + p2.y + bb.y, 0.f);
  r.z = fmaxf(p0.z + p1.z + p2.z + bb.z, 0.f);
  r.w = fmaxf(p0.w + p1.w + p2.w + bb.w, 0.f);
  *(float4*)(x2 + (size_t)i4 * 4) = r;
}

// --------------------------- 1x1 heads GEMM --------------------------------
// logits[m][0..63] = x2[m][:] @ Wco + bco   (grid 40)
__global__ __launch_bounds__(256) void gemm1x1(const float* __restrict__ x2,
                                               const float* __restrict__ Wco,
                                               const float* __restrict__ bco,
                                               float* __restrict__ logits) {
  __shared__ __align__(16) float At[32][68];
  __shared__ __align__(16) float Bt[32][64];
  int tid = threadIdx.x;
  int m0 = blockIdx.x << 6;
  int ti = tid >> 4, tj = tid & 15;
  int si = tid >> 2, sq = tid & 3;
  int skk = tid >> 3, sr = tid & 7;
  float acc[4][4] = {{0.f}};
  int m = m0 + si;
  bool mv = m < NM;
  const float* arow = x2 + (((size_t)(mv ? m : 0)) << 9);
  for (int c0 = 0; c0 < CIN; c0 += 32) {
    __syncthreads();
    float4 a0 = make_float4(0.f, 0.f, 0.f, 0.f), a1 = a0;
    if (mv) {
      a0 = *(const float4*)(arow + c0 + (sq << 2));
      a1 = *(const float4*)(arow + c0 + 16 + (sq << 2));
    }
    int kb = sq << 2;
    At[kb + 0][si] = a0.x; At[kb + 1][si] = a0.y; At[kb + 2][si] = a0.z; At[kb + 3][si] = a0.w;
    At[kb + 16][si] = a1.x; At[kb + 17][si] = a1.y; At[kb + 18][si] = a1.z; At[kb + 19][si] = a1.w;
    const float* bp = Wco + (size_t)(c0 + skk) * 64;
    *(float4*)&Bt[skk][sr << 2] = *(const float4*)(bp + (sr << 2));
    *(float4*)&Bt[skk][32 + (sr << 2)] = *(const float4*)(bp + 32 + (sr << 2));
    __syncthreads();
#pragma unroll
    for (int kk = 0; kk < 32; kk++) {
      float4 avv = *(const float4*)&At[kk][ti << 2];
      float4 bvv = *(const float4*)&Bt[kk][tj << 2];
      float a_[4] = {avv.x, avv.y, avv.z, avv.w};
      float b_[4] = {bvv.x, bvv.y, bvv.z, bvv.w};
#pragma unroll
      for (int u = 0; u < 4; u++)
#pragma unroll
        for (int v = 0; v < 4; v++) acc[u][v] += a_[u] * b_[v];
    }
  }
  float4 bias = *(const float4*)(bco + (tj << 2));
#pragma unroll
  for (int u = 0; u < 4; u++) {
    int mr = m0 + (ti << 2) + u;
    if (mr < NM) {
      float4 r = make_float4(acc[u][0] + bias.x, acc[u][1] + bias.y, acc[u][2] + bias.z,
                             acc[u][3] + bias.w);
      *(float4*)(logits + (size_t)mr * 64 + (tj << 2)) = r;
    }
  }
}

// --------------------------- scores + proposals ----------------------------
__global__ __launch_bounds__(256) void score_box_kernel(const float* __restrict__ logits,
                                                        const int* __restrict__ ih,
                                                        const int* __restrict__ iw,
                                                        BaseAnchors ba,
                                                        float* __restrict__ scores,
                                                        float* __restrict__ props) {
#pragma clang fp contract(off)
  int n = blockIdx.x * 256 + threadIdx.x;
  if (n >= NBATCH * NANCH) return;
  int b = n / NANCH;
  int r = n % NANCH;
  int pos = r / 9, aa = r % 9;
  int py = pos / HWDIM, px = pos % HWDIM;
  const float* L = logits + (size_t)(b * NPOS + pos) * 64;
  float l0 = L[2 * aa], l1 = L[2 * aa + 1];
  float mx = fmaxf(l0, l1);
  float e0 = expf(l0 - mx), e1 = expf(l1 - mx);
  float s = e1 / (e0 + e1);
  float d0 = L[18 + 4 * aa + 0], d1 = L[18 + 4 * aa + 1];
  float d2 = L[18 + 4 * aa + 2], d3 = L[18 + 4 * aa + 3];
  float xf = (float)px * 32.f, yf = (float)py * 32.f;
  float ax1 = ba.x1[aa] + xf, ay1 = ba.y1[aa] + yf;
  float ax2 = ba.x2[aa] + xf, ay2 = ba.y2[aa] + yf;
  float wA = ax2 - ax1, hA = ay2 - ay1;
  float cx = ax1 + 0.5f * wA, cy = ay1 + 0.5f * hA;
  float pcx = d0 * wA + cx, pcy = d1 * hA + cy;
  float pw = expf(d2) * wA, ph = expf(d3) * hA;
  float x1 = pcx - 0.5f * pw, y1 = pcy - 0.5f * ph;
  float x2 = pcx + 0.5f * pw, y2 = pcy + 0.5f * ph;
  float W = (float)iw[0], H = (float)ih[0];
  x1 = fminf(fmaxf(x1, 0.f), W);
  y1 = fminf(fmaxf(y1, 0.f), H);
  x2 = fminf(fmaxf(x2, 0.f), W);
  y2 = fminf(fmaxf(y2, 0.f), H);
  scores[n] = s;
  *(float4*)(props + (size_t)n * 4) = make_float4(x1, y1, x2, y2);
}

// --------------------------- sort (bitonic, stable ties) -------------------
__global__ __launch_bounds__(1024) void sort_kernel(const float* __restrict__ scores,
                                                    const float* __restrict__ props,
                                                    int* __restrict__ order,
                                                    float* __restrict__ sb) {
  __shared__ u64 keys[8192];
  int b = blockIdx.x, tid = threadIdx.x;
  const float* sc = scores + (size_t)b * NANCH;
  for (int i = tid; i < 8192; i += 1024) {
    u64 k = 0ull;
    if (i < NANCH) {
      unsigned int sbits = __float_as_uint(sc[i]);  // scores > 0 -> order-preserving bits
      k = (((u64)sbits) << 32) | (u64)(~(unsigned int)i);
    }
    keys[i] = k;
  }
  __syncthreads();
  for (int k = 2; k <= 8192; k <<= 1) {
    for (int j = k >> 1; j > 0; j >>= 1) {
#pragma unroll
      for (int s = 0; s < 8; s++) {
        int i = tid + (s << 10);
        int p = i ^ j;
        if (p > i) {
          u64 a = keys[i], c = keys[p];
          bool up = ((i & k) == 0);
          bool sw = up ? (a < c) : (a > c);  // descending overall
          if (sw) { keys[i] = c; keys[p] = a; }
        }
      }
      __syncthreads();
    }
  }
  for (int i = tid; i < NANCH; i += 1024) {
    u64 kk = keys[i];
    int orig = (int)(~(unsigned int)kk);
    order[b * NANCH + i] = orig;
    float4 p = *(const float4*)(props + ((size_t)b * NANCH + orig) * 4);
    *(float4*)(sb + ((size_t)b * NANCH + i) * 4) = p;
  }
}

// --------------------------- NMS bitmask (SPARSE lists) --------------------
// Off-diagonal nonzero words appended to lists[b][cb]: (bitsLo, bitsHi, row).
// Append order nondeterministic (atomics) but consumption is a masked OR ->
// result deterministic. Diagonal blocks stored dense in maskd[b][s][lane].
__global__ __launch_bounds__(64) void nms_mask_kernel(const float* __restrict__ sb,
                                                      uint4* __restrict__ lists,
                                                      u32* __restrict__ cnt,
                                                      u64* __restrict__ maskd) {
#pragma clang fp contract(off)
  int rb = blockIdx.x, cb = blockIdx.y, b = blockIdx.z;
  if (cb < rb) return;
  int lane = threadIdx.x;
  __shared__ float4 cbox[64];
  int j0 = cb << 6;
  const float* sbb = sb + (size_t)b * NANCH * 4;
  if (j0 + lane < NANCH) cbox[lane] = *(const float4*)(sbb + (size_t)(j0 + lane) * 4);
  __syncthreads();
  int i = (rb << 6) + lane;
  if (i >= NANCH) return;
  float4 rbox = *(const float4*)(sbb + (size_t)i * 4);
  float rarea = (rbox.z - rbox.x) * (rbox.w - rbox.y);
  u64 bits = 0ull;
  int jmax = NANCH - j0;
  if (jmax > 64) jmax = 64;
  for (int l = 0; l < jmax; l++) {
    int j = j0 + l;
    if (j > i) {
      float4 c = cbox[l];
      float carea = (c.z - c.x) * (c.w - c.y);
      float ltx = fmaxf(rbox.x, c.x), lty = fmaxf(rbox.y, c.y);
      float rbx = fminf(rbox.z, c.z), rby = fminf(rbox.w, c.w);
      float wx = fmaxf(rbx - ltx, 0.f);
      float wy = fmaxf(rby - lty, 0.f);
      float inter = wx * wy;
      float iou = inter / (rarea + carea - inter);  // 0/0 -> NaN -> compare false
      if (iou > 0.7f) bits |= (1ull << l);
    }
  }
  if (rb == cb) {
    maskd[((size_t)b * NW + rb) * 64 + lane] = bits;
  } else if (bits) {
    u32 idx = atomicAdd(&cnt[b * NW + cb], 1u);
    if (idx < CAP)
      lists[((size_t)(b * NW + cb)) * CAP + idx] =
          make_uint4((u32)bits, (u32)(bits >> 32), (u32)i, 0u);
  }
}

// --------------------------- NMS scan (sparse, 1 wave, no barriers) --------
// Per stripe s: cur = OR over keep-masked list entries; ctz chain over rows
// with nonzero diagonal out-edges. List head (first 64 entries) AND diagonal
// for stripe s+1 prefetched during stripe s (loop-carried registers).
__global__ __launch_bounds__(64, 1) void nms_scan_kernel(const uint4* __restrict__ lists,
                                                         const u32* __restrict__ cnt,
                                                         const u64* __restrict__ maskd,
                                                         const int* __restrict__ order,
                                                         const float* __restrict__ sb,
                                                         float* __restrict__ out) {
  int b = blockIdx.x;
  int lane = threadIdx.x;
  __shared__ u64 keep_sh[NW];
  const u64* md = maskd + (size_t)b * NW * 64;
  const uint4* lb = lists + (size_t)b * NW * CAP;

  // counts into registers: lane l holds cnt[l] and cnt[l+64]
  u32 c0 = (lane < NW) ? cnt[b * NW + lane] : 0u;
  u32 c1 = (lane + 64 < NW) ? cnt[b * NW + lane + 64] : 0u;

  u64 diag = md[lane];   // stripe 0 diagonal (coalesced)
  uint4 pf = lb[lane];   // stripe 0 list head prefetch
  for (int s = 0; s < NW; s++) {
    u64 Mw = diag;
    uint4 e0 = pf;
    if (s + 1 < NW) {
      diag = md[((s + 1) << 6) + lane];          // loop-carried prefetch
      pf = lb[(size_t)(s + 1) * CAP + lane];     // next list head in flight
    }

    int cn = (int)(u32)__builtin_amdgcn_readlane(
        (int)((s < 64) ? c0 : c1), (s < 64) ? s : s - 64);
    if (cn > CAP) cn = CAP;

    // gather: OR keep-masked list entries (first 64 from prefetch)
    u64 acc = 0ull;
    if (lane < cn) {
      u64 kw = keep_sh[e0.z >> 6];
      if ((kw >> (e0.z & 63)) & 1ull) acc |= (((u64)e0.y) << 32) | (u64)e0.x;
    }
    for (int p = lane + 64; p < cn; p += 64) {
      uint4 e = lb[(size_t)s * CAP + p];
      u64 kw = keep_sh[e.z >> 6];
      if ((kw >> (e.z & 63)) & 1ull) acc |= (((u64)e.y) << 32) | (u64)e.x;
    }
    u64 cur = waveOr64(acc);

    int nrows = NANCH - (s << 6);
    if (nrows > 64) nrows = 64;
    u64 valid = (nrows < 64) ? ((1ull << nrows) - 1ull) : ~0ull;

    // chain over rows with nonzero out-edges only
    u64 nz = __ballot(Mw != 0ull);
    u64 todo = nz & ~cur & valid;
    while (todo) {
      int t = (int)__builtin_ctzll(todo);
      cur |= bcast64(Mw, t);
      todo &= ~cur;
      todo &= ~(1ull << t);
    }
    u64 alive = (~cur) & valid;
    if (lane == 0) keep_sh[s] = alive;  // same-wave LDS, no barrier needed
  }

  // write output: out[b][orig] = kept ? sorted_box : 0
  for (int i = lane; i < NANCH; i += 64) {
    u64 kw = keep_sh[i >> 6];
    bool kept = ((kw >> (i & 63)) & 1ull) != 0ull;
    int orig = order[b * NANCH + i];
    float4 p = *(const float4*)(sb + ((size_t)b * NANCH + i) * 4);
    float4 o = kept ? p : make_float4(0.f, 0.f, 0.f, 0.f);
    *(float4*)(out + ((size_t)b * NANCH + orig) * 4) = o;
  }
}

// --------------------------- host launcher ---------------------------------

extern "C" void kernel_launch(void* const* d_in, const int* in_sizes, int n_in,
                              void* d_out, int out_size, void* d_ws, size_t ws_size,
                              hipStream_t stream) {
  const float* features = (const float*)d_in[0];
  const float* conv_w   = (const float*)d_in[1];
  const float* conv_b   = (const float*)d_in[2];
  const float* cls_w    = (const float*)d_in[3];
  const float* cls_b    = (const float*)d_in[4];
  const float* bbox_w   = (const float*)d_in[5];
  const float* bbox_b   = (const float*)d_in[6];
  const int*   img_h    = (const int*)d_in[7];
  const int*   img_w    = (const int*)d_in[8];
  float* out = (float*)d_out;
  char* ws = (char*)d_ws;

  // workspace layout (bytes); NMS arrays alias FM/WT/XP (dead by NMS time)
  const size_t OFF_FM    = 0;                  // 5,120,000
  const size_t OFF_WT    = 5120000;            // 9,437,184
  const size_t OFF_XP    = 14557184;           // 15,360,000 (ends 29,917,184)
  const size_t OFF_LISTS = 0;                  // 23,068,672 (4*88*4096*16)
  const size_t OFF_CNT   = 23068672;           // 1,408 -> pad to 23,070,208
  const size_t OFF_MASKD = 23070208;           // 180,224 (ends 23,250,432)
  const size_t OFF_X2  = 29917184;             // 5,120,000
  const size_t OFF_WCO = 35037184;             // 131,072
  const size_t OFF_BCO = 35168256;             // 256
  const size_t OFF_LOG = 35168512;             // 640,000
  const size_t OFF_SC  = 35808512;             // 90,000
  const size_t OFF_PR  = 35898512;             // 360,000
  const size_t OFF_ORD = 36258512;             // 90,000
  const size_t OFF_SB  = 36348512;             // 360,000
  const size_t WS_NEEDED = 36708512;
  if (ws_size < WS_NEEDED) return;

  float* fm   = (float*)(ws + OFF_FM);
  float* Wt   = (float*)(ws + OFF_WT);
  float* xp   = (float*)(ws + OFF_XP);
  uint4* lists = (uint4*)(ws + OFF_LISTS);
  u32*   cnt   = (u32*)(ws + OFF_CNT);
  u64*   maskd = (u64*)(ws + OFF_MASKD);
  float* x2   = (float*)(ws + OFF_X2);
  float* Wco  = (float*)(ws + OFF_WCO);
  float* bco  = (float*)(ws + OFF_BCO);
  float* logits = (float*)(ws + OFF_LOG);
  float* scores = (float*)(ws + OFF_SC);
  float* props  = (float*)(ws + OFF_PR);
  int*   order  = (int*)(ws + OFF_ORD);
  float* sb     = (float*)(ws + OFF_SB);

  // base anchors in double, rounded to f32 exactly like numpy
  BaseAnchors ba;
  {
    const double scales[3] = {64.0, 128.0, 256.0};
    const double ratios[3] = {0.5, 1.0, 2.0};
    int a = 0;
    for (int si = 0; si < 3; si++)
      for (int ri = 0; ri < 3; ri++, a++) {
        double w = scales[si] * sqrt(ratios[ri]);
        double h = scales[si] / sqrt(ratios[ri]);
        ba.x1[a] = (float)(-w / 2.0);
        ba.y1[a] = (float)(-h / 2.0);
        ba.x2[a] = (float)(w / 2.0);
        ba.y2[a] = (float)(h / 2.0);
      }
  }

  transpose_features<<<dim3(20, 16, 4), dim3(32, 8), 0, stream>>>(features, fm);
  transpose_weights<<<dim3(16, 16), 256, 0, stream>>>(conv_w, Wt);
  build_wco<<<128, 256, 0, stream>>>(cls_w, cls_b, bbox_w, bbox_b, Wco, bco);
  conv_gemm<<<dim3(40, 8, 3), 256, 0, stream>>>(fm, Wt, xp);
  combine_relu<<<1250, 256, 0, stream>>>(xp, conv_b, x2);
  gemm1x1<<<40, 256, 0, stream>>>(x2, Wco, bco, logits);
  score_box_kernel<<<88, 256, 0, stream>>>(logits, img_h, img_w, ba, scores, props);
  sort_kernel<<<4, 1024, 0, stream>>>(scores, props, order, sb);
  zero_cnt<<<6, 64, 0, stream>>>(cnt);
  nms_mask_kernel<<<dim3(NW, NW, 4), 64, 0, stream>>>(sb, lists, cnt, maskd);
  nms_scan_kernel<<<4, 64, 0, stream>>>(lists, cnt, maskd, order, sb, out);
}

// Round 13
// 390.039 us; speedup vs baseline: 1.4865x; 1.1729x over previous
//
#include <hip/hip_runtime.h>

// ---------------------------------------------------------------------------
// RPN forward: conv3x3(512->512)+relu, 1x1 heads (18 cls, 36 bbox),
// anchor decode + clip, softmax score, greedy NMS (0.7), keep-masked boxes.
// All decision math in fp32 with contraction OFF to track the numpy reference.
// R13: sort replaced: 8192-key bitonic (91 LDS+barrier stages, est ~90us on
//   4 blocks) -> 4-pass LSD radix (8-bit digits, descending, stable; per-wave
//   contiguous ranges keep argsort(-scores) tie order). conv_gemm = R12
//   (178us, frozen). NMS = R8 sparse lists + R11 prefetched 1-wave scan.
// ---------------------------------------------------------------------------

#define NBATCH 4
#define HWDIM  25
#define NPOS   625            // 25*25
#define NM     2500           // NBATCH*NPOS
#define CIN    512
#define NANCH  5625           // NPOS*9
#define NW     88             // ceil(NANCH/64)
#define CAP    4096           // list capacity per (b, colword)
#define SORTN  6144           // 6 rounds * 1024 threads (padded with sentinels)

typedef unsigned long long u64;
typedef unsigned int u32;

struct BaseAnchors { float x1[9], y1[9], x2[9], y2[9]; };

__device__ __forceinline__ u64 bcast64(u64 v, int lane) {
  unsigned int lo = (unsigned int)v;
  unsigned int hi = (unsigned int)(v >> 32);
  lo = (unsigned int)__builtin_amdgcn_readlane((int)lo, lane);
  hi = (unsigned int)__builtin_amdgcn_readlane((int)hi, lane);
  return (((u64)hi) << 32) | (u64)lo;
}

__device__ __forceinline__ u64 waveOr64(u64 x) {
  unsigned int lo = (unsigned int)x, hi = (unsigned int)(x >> 32);
#pragma unroll
  for (int off = 32; off > 0; off >>= 1) {
    lo |= (unsigned int)__shfl_xor((int)lo, off, 64);
    hi |= (unsigned int)__shfl_xor((int)hi, off, 64);
  }
  return (((u64)hi) << 32) | (u64)lo;
}

// --------------------------- prep: transposes ------------------------------

// f[b][c][pos] -> fm[b*625+pos][c]
__global__ void transpose_features(const float* __restrict__ f, float* __restrict__ fm) {
  __shared__ float tile[32][33];
  int b  = blockIdx.z;
  int p0 = blockIdx.x * 32;
  int c0 = blockIdx.y * 32;
  int tx = threadIdx.x, ty = threadIdx.y;  // (32, 8)
#pragma unroll
  for (int j = 0; j < 4; j++) {
    int c = c0 + ty + j * 8;
    int p = p0 + tx;
    if (p < NPOS) tile[ty + j * 8][tx] = f[((size_t)(b * CIN + c)) * NPOS + p];
  }
  __syncthreads();
#pragma unroll
  for (int j = 0; j < 4; j++) {
    int p = p0 + ty + j * 8;
    int c = c0 + tx;
    if (p < NPOS) fm[((size_t)(b * NPOS + p)) * CIN + c] = tile[tx][ty + j * 8];
  }
}

// conv_w[o][c][tap] -> Wt[tap][c][o]
__global__ __launch_bounds__(256) void transpose_weights(const float* __restrict__ cw,
                                                         float* __restrict__ Wt) {
  __shared__ float tile[32][289];
  int o0 = blockIdx.x * 32, c0 = blockIdx.y * 32;
  int tid = threadIdx.x;
#pragma unroll
  for (int j = 0; j < 36; j++) {
    int idx = tid + j * 256;            // 0..9215
    int o = idx / 288, kk = idx % 288;  // kk = c_rel*9 + tap
    tile[o][kk] = cw[((size_t)(o0 + o)) * 4608 + c0 * 9 + kk];
  }
  __syncthreads();
  int ol = tid & 31, pg = tid >> 5;  // 0..7
#pragma unroll
  for (int j = 0; j < 36; j++) {
    int pair = pg + j * 8;  // 0..287 == c_rel*9 + tap
    int c = pair / 9, tap = pair % 9;
    Wt[((size_t)tap * CIN + (c0 + c)) * 512 + o0 + ol] = tile[ol][pair];
  }
}

// combined 1x1 head weights: Wco[c][o] (o: 0..17 cls, 18..53 bbox, 54..63 zero)
__global__ void build_wco(const float* __restrict__ clsw, const float* __restrict__ clsb,
                          const float* __restrict__ bw, const float* __restrict__ bbb,
                          float* __restrict__ Wco, float* __restrict__ bco) {
  int idx = blockIdx.x * 256 + threadIdx.x;
  if (idx < 512 * 64) {
    int c = idx >> 6, o = idx & 63;
    float v = 0.f;
    if (o < 18) v = clsw[o * 512 + c];
    else if (o < 54) v = bw[(o - 18) * 512 + c];
    Wco[idx] = v;
  }
  if (idx < 64) {
    float v = 0.f;
    if (idx < 18) v = clsb[idx];
    else if (idx < 54) v = bbb[idx - 18];
    bco[idx] = v;
  }
}

__global__ void zero_cnt(u32* __restrict__ cnt) {
  int i = blockIdx.x * 64 + threadIdx.x;
  if (i < NBATCH * NW) cnt[i] = 0u;
}

// --------------------------- conv3x3 implicit GEMM -------------------------
// grid (40, 8, 3): 64 m-rows x 64 o-cols per block, part = 3 taps (dy fixed).
// R12 version (178us): static load/use rotation, FMA order == R8.
__global__ __launch_bounds__(256) void conv_gemm(const float* __restrict__ fm,
                                                 const float* __restrict__ Wt,
                                                 float* __restrict__ xp) {
  __shared__ __align__(16) float At[32][68];
  __shared__ __align__(16) float Bt[32][64];
  int tid = threadIdx.x;
  int m0 = blockIdx.x << 6;
  int o0 = blockIdx.y << 6;
  int part = blockIdx.z;  // 0..2 -> dy = part-1
  int ti = tid >> 4, tj = tid & 15;   // compute tile 4x4
  int si = tid >> 2, sq = tid & 3;    // A staging: row si, col quad sq
  int skk = tid >> 3, sr = tid & 7;   // B staging: k-row skk, col oct sr
  float acc[4][4] = {{0.f}};

  int m = m0 + si;
  bool mv = m < NM;
  int mm = mv ? m : 0;
  int bb = mm / NPOS, rem = mm % NPOS;
  int hh = rem / HWDIM, ww = rem % HWDIM;
  int dy = part - 1;

  for (int tt = 0; tt < 3; tt++) {
    int tap = part * 3 + tt;
    int dx = tt - 1;
    int h2 = hh + dy, w2 = ww + dx;
    bool av = mv && ((unsigned)h2 < (unsigned)HWDIM) && ((unsigned)w2 < (unsigned)HWDIM);
    const float* arow = fm + (((size_t)(bb * NPOS + h2 * HWDIM + w2)) << 9);
    const float* bbase = Wt + (((size_t)tap) << 18) + o0;

    // prologue: load c0=0 tile into registers
    float4 a0 = make_float4(0.f, 0.f, 0.f, 0.f), a1 = a0;
    if (av) {
      a0 = *(const float4*)(arow + (sq << 2));
      a1 = *(const float4*)(arow + 16 + (sq << 2));
    }
    const float* bp0 = bbase + (((size_t)skk) << 9);
    float4 b0 = *(const float4*)(bp0 + (sr << 2));
    float4 b1 = *(const float4*)(bp0 + 32 + (sr << 2));

    for (int c0 = 0; c0 < CIN; c0 += 32) {
      __syncthreads();
      // write current tile (loaded last iteration / prologue)
      int kb = sq << 2;
      At[kb + 0][si] = a0.x; At[kb + 1][si] = a0.y; At[kb + 2][si] = a0.z; At[kb + 3][si] = a0.w;
      At[kb + 16][si] = a1.x; At[kb + 17][si] = a1.y; At[kb + 18][si] = a1.z; At[kb + 19][si] = a1.w;
      *(float4*)&Bt[skk][sr << 2] = b0;
      *(float4*)&Bt[skk][32 + (sr << 2)] = b1;
      // issue next tile's loads (land during compute below)
      float4 na0 = make_float4(0.f, 0.f, 0.f, 0.f), na1 = na0;
      float4 nb0 = na0, nb1 = na0;
      int c1 = c0 + 32;
      if (c1 < CIN) {
        if (av) {
          na0 = *(const float4*)(arow + c1 + (sq << 2));
          na1 = *(const float4*)(arow + c1 + 16 + (sq << 2));
        }
        const float* bp = bbase + (((size_t)(c1 + skk)) << 9);
        nb0 = *(const float4*)(bp + (sr << 2));
        nb1 = *(const float4*)(bp + 32 + (sr << 2));
      }
      __syncthreads();
#pragma unroll
      for (int kk = 0; kk < 32; kk++) {
        float4 avv = *(const float4*)&At[kk][ti << 2];
        float4 bvv = *(const float4*)&Bt[kk][tj << 2];
        float a_[4] = {avv.x, avv.y, avv.z, avv.w};
        float b_[4] = {bvv.x, bvv.y, bvv.z, bvv.w};
#pragma unroll
        for (int u = 0; u < 4; u++)
#pragma unroll
          for (int v = 0; v < 4; v++) acc[u][v] += a_[u] * b_[v];
      }
      a0 = na0; a1 = na1; b0 = nb0; b1 = nb1;
    }
  }
  float* outp = xp + (size_t)part * (NM * 512);
#pragma unroll
  for (int u = 0; u < 4; u++) {
    int mr = m0 + (ti << 2) + u;
    if (mr < NM) {
      float4 r = make_float4(acc[u][0], acc[u][1], acc[u][2], acc[u][3]);
      *(float4*)(outp + (((size_t)mr) << 9) + o0 + (tj << 2)) = r;
    }
  }
}

// x2 = relu(xp0+xp1+xp2+bias)
__global__ void combine_relu(const float* __restrict__ xp, const float* __restrict__ bias,
                             float* __restrict__ x2) {
  int i4 = blockIdx.x * 256 + threadIdx.x;  // over 320000 float4s
  if (i4 >= NM * 128) return;
  float4 p0 = *(const float4*)(xp + (size_t)i4 * 4);
  float4 p1 = *(const float4*)(xp + (size_t)(NM * 512) + (size_t)i4 * 4);
  float4 p2 = *(const float4*)(xp + (size_t)(2 * NM * 512) + (size_t)i4 * 4);
  float4 bb = *(const float4*)(bias + (i4 & 127) * 4);
  float4 r;
  r.x = fmaxf(p0.x + p1.x + p2.x + bb.x, 0.f);
  r.y = fmaxf(p0.y + p1.y + p2.y + bb.y, 0.f);
  r.z = fmaxf(p0.z + p1.z + p2.z + bb.z, 0.f);
  r.w = fmaxf(p0.w + p1.w + p2.w + bb.w, 0.f);
  *(float4*)(x2 + (size_t)i4 * 4) = r;
}

// --------------------------- 1x1 heads GEMM --------------------------------
// logits[m][0..63] = x2[m][:] @ Wco + bco   (grid 40)
__global__ __launch_bounds__(256) void gemm1x1(const float* __restrict__ x2,
                                               const float* __restrict__ Wco,
                                               const float* __restrict__ bco,
                                               float* __restrict__ logits) {
  __shared__ __align__(16) float At[32][68];
  __shared__ __align__(16) float Bt[32][64];
  int tid = threadIdx.x;
  int m0 = blockIdx.x << 6;
  int ti = tid >> 4, tj = tid & 15;
  int si = tid >> 2, sq = tid & 3;
  int skk = tid >> 3, sr = tid & 7;
  float acc[4][4] = {{0.f}};
  int m = m0 + si;
  bool mv = m < NM;
  const float* arow = x2 + (((size_t)(mv ? m : 0)) << 9);
  for (int c0 = 0; c0 < CIN; c0 += 32) {
    __syncthreads();
    float4 a0 = make_float4(0.f, 0.f, 0.f, 0.f), a1 = a0;
    if (mv) {
      a0 = *(const float4*)(arow + c0 + (sq << 2));
      a1 = *(const float4*)(arow + c0 + 16 + (sq << 2));
    }
    int kb = sq << 2;
    At[kb + 0][si] = a0.x; At[kb + 1][si] = a0.y; At[kb + 2][si] = a0.z; At[kb + 3][si] = a0.w;
    At[kb + 16][si] = a1.x; At[kb + 17][si] = a1.y; At[kb + 18][si] = a1.z; At[kb + 19][si] = a1.w;
    const float* bp = Wco + (size_t)(c0 + skk) * 64;
    *(float4*)&Bt[skk][sr << 2] = *(const float4*)(bp + (sr << 2));
    *(float4*)&Bt[skk][32 + (sr << 2)] = *(const float4*)(bp + 32 + (sr << 2));
    __syncthreads();
#pragma unroll
    for (int kk = 0; kk < 32; kk++) {
      float4 avv = *(const float4*)&At[kk][ti << 2];
      float4 bvv = *(const float4*)&Bt[kk][tj << 2];
      float a_[4] = {avv.x, avv.y, avv.z, avv.w};
      float b_[4] = {bvv.x, bvv.y, bvv.z, bvv.w};
#pragma unroll
      for (int u = 0; u < 4; u++)
#pragma unroll
        for (int v = 0; v < 4; v++) acc[u][v] += a_[u] * b_[v];
    }
  }
  float4 bias = *(const float4*)(bco + (tj << 2));
#pragma unroll
  for (int u = 0; u < 4; u++) {
    int mr = m0 + (ti << 2) + u;
    if (mr < NM) {
      float4 r = make_float4(acc[u][0] + bias.x, acc[u][1] + bias.y, acc[u][2] + bias.z,
                             acc[u][3] + bias.w);
      *(float4*)(logits + (size_t)mr * 64 + (tj << 2)) = r;
    }
  }
}

// --------------------------- scores + proposals ----------------------------
__global__ __launch_bounds__(256) void score_box_kernel(const float* __restrict__ logits,
                                                        const int* __restrict__ ih,
                                                        const int* __restrict__ iw,
                                                        BaseAnchors ba,
                                                        float* __restrict__ scores,
                                                        float* __restrict__ props) {
#pragma clang fp contract(off)
  int n = blockIdx.x * 256 + threadIdx.x;
  if (n >= NBATCH * NANCH) return;
  int b = n / NANCH;
  int r = n % NANCH;
  int pos = r / 9, aa = r % 9;
  int py = pos / HWDIM, px = pos % HWDIM;
  const float* L = logits + (size_t)(b * NPOS + pos) * 64;
  float l0 = L[2 * aa], l1 = L[2 * aa + 1];
  float mx = fmaxf(l0, l1);
  float e0 = expf(l0 - mx), e1 = expf(l1 - mx);
  float s = e1 / (e0 + e1);
  float d0 = L[18 + 4 * aa + 0], d1 = L[18 + 4 * aa + 1];
  float d2 = L[18 + 4 * aa + 2], d3 = L[18 + 4 * aa + 3];
  float xf = (float)px * 32.f, yf = (float)py * 32.f;
  float ax1 = ba.x1[aa] + xf, ay1 = ba.y1[aa] + yf;
  float ax2 = ba.x2[aa] + xf, ay2 = ba.y2[aa] + yf;
  float wA = ax2 - ax1, hA = ay2 - ay1;
  float cx = ax1 + 0.5f * wA, cy = ay1 + 0.5f * hA;
  float pcx = d0 * wA + cx, pcy = d1 * hA + cy;
  float pw = expf(d2) * wA, ph = expf(d3) * hA;
  float x1 = pcx - 0.5f * pw, y1 = pcy - 0.5f * ph;
  float x2 = pcx + 0.5f * pw, y2 = pcy + 0.5f * ph;
  float W = (float)iw[0], H = (float)ih[0];
  x1 = fminf(fmaxf(x1, 0.f), W);
  y1 = fminf(fmaxf(y1, 0.f), H);
  x2 = fminf(fmaxf(x2, 0.f), W);
  y2 = fminf(fmaxf(y2, 0.f), H);
  scores[n] = s;
  *(float4*)(props + (size_t)n * 4) = make_float4(x1, y1, x2, y2);
}

// --------------------------- sort (LSD radix, stable) ----------------------
// 4 passes x 8 bits on score bits (positive floats -> unsigned order), bucket
// = 255-digit for DESCENDING. Stability == jnp.argsort(-scores): each wave
// owns a CONTIGUOUS 384-element range, so (wave, round, lane) == global index
// order; per-wave cursors consumed in that order. Sentinels (key 0, idx>=
// NANCH) start after all real elements and stay there under stable ties.
__global__ __launch_bounds__(1024, 1) void radix_sort_kernel(const float* __restrict__ scores,
                                                             const float* __restrict__ props,
                                                             int* __restrict__ order,
                                                             float* __restrict__ sb) {
  __shared__ u32 kA[SORTN], vA[SORTN], kB[SORTN], vB[SORTN];
  __shared__ u32 hist[16][256];
  __shared__ u32 tot[256], base[256], tmp[256];
  int b = blockIdx.x, tid = threadIdx.x;
  int lane = tid & 63, wv = tid >> 6;
  const float* sc = scores + (size_t)b * NANCH;

  for (int i = tid; i < SORTN; i += 1024) {
    kA[i] = (i < NANCH) ? __float_as_uint(sc[i]) : 0u;
    vA[i] = (u32)i;
  }
  __syncthreads();

  for (int pass = 0; pass < 4; pass++) {
    int shift = pass << 3;
    u32* ks = (pass & 1) ? kB : kA;
    u32* vs = (pass & 1) ? vB : vA;
    u32* kd = (pass & 1) ? kA : kB;
    u32* vd = (pass & 1) ? vA : vB;
    // zero histograms
    for (int i = tid; i < 4096; i += 1024) ((u32*)hist)[i] = 0u;
    __syncthreads();
    // count (wave-contiguous ranges: i = wv*384 + r*64 + lane)
    for (int r = 0; r < 6; r++) {
      int i = wv * 384 + (r << 6) + lane;
      u32 d = 255u - ((ks[i] >> shift) & 255u);
      atomicAdd(&hist[wv][d], 1u);
    }
    __syncthreads();
    // per-bucket across-wave exclusive prefix + bucket totals
    if (tid < 256) {
      u32 run = 0;
#pragma unroll
      for (int w = 0; w < 16; w++) { u32 t = hist[w][tid]; hist[w][tid] = run; run += t; }
      tot[tid] = run;
    }
    __syncthreads();
    // exclusive scan of tot[256] -> base (Hillis-Steele)
    if (tid < 256) tmp[tid] = tot[tid];
    __syncthreads();
    for (int off = 1; off < 256; off <<= 1) {
      u32 v = 0;
      if (tid < 256 && tid >= off) v = tmp[tid - off];
      __syncthreads();
      if (tid < 256) tmp[tid] += v;
      __syncthreads();
    }
    if (tid < 256) base[tid] = tmp[tid] - tot[tid];
    __syncthreads();
    if (tid < 256) {
      u32 bs = base[tid];
#pragma unroll
      for (int w = 0; w < 16; w++) hist[w][tid] += bs;
    }
    __syncthreads();
    // stable scatter: rounds in order; in-wave rank via 8-bit multi-split
    for (int r = 0; r < 6; r++) {
      int i = wv * 384 + (r << 6) + lane;
      u32 key = ks[i], val = vs[i];
      u32 d = 255u - ((key >> shift) & 255u);
      u64 grp = ~0ull;
#pragma unroll
      for (int bit = 0; bit < 8; bit++) {
        u64 bal = __ballot(((d >> bit) & 1u) != 0u);
        grp &= ((d >> bit) & 1u) ? bal : ~bal;
      }
      u64 ltmask = (1ull << lane) - 1ull;
      u32 rank = (u32)__popcll(grp & ltmask);
      int leader = (int)__builtin_ctzll(grp);
      u32 oldv = 0;
      if (lane == leader) oldv = atomicAdd(&hist[wv][d], (u32)__popcll(grp));
      oldv = (u32)__shfl((int)oldv, leader, 64);
      u32 slot = oldv + rank;
      kd[slot] = key;
      vd[slot] = val;
    }
    __syncthreads();
  }

  // after 4 passes result is in kA/vA; emit order + sorted boxes
  const float* pr = props + (size_t)b * NANCH * 4;
  for (int i = tid; i < NANCH; i += 1024) {
    u32 orig = vA[i];
    order[b * NANCH + i] = (int)orig;
    float4 p = *(const float4*)(pr + (size_t)orig * 4);
    *(float4*)(sb + ((size_t)b * NANCH + i) * 4) = p;
  }
}

// --------------------------- NMS bitmask (SPARSE lists) --------------------
// Off-diagonal nonzero words appended to lists[b][cb]: (bitsLo, bitsHi, row).
// Append order nondeterministic (atomics) but consumption is a masked OR ->
// result deterministic. Diagonal blocks stored dense in maskd[b][s][lane].
__global__ __launch_bounds__(64) void nms_mask_kernel(const float* __restrict__ sb,
                                                      uint4* __restrict__ lists,
                                                      u32* __restrict__ cnt,
                                                      u64* __restrict__ maskd) {
#pragma clang fp contract(off)
  int rb = blockIdx.x, cb = blockIdx.y, b = blockIdx.z;
  if (cb < rb) return;
  int lane = threadIdx.x;
  __shared__ float4 cbox[64];
  int j0 = cb << 6;
  const float* sbb = sb + (size_t)b * NANCH * 4;
  if (j0 + lane < NANCH) cbox[lane] = *(const float4*)(sbb + (size_t)(j0 + lane) * 4);
  __syncthreads();
  int i = (rb << 6) + lane;
  if (i >= NANCH) return;
  float4 rbox = *(const float4*)(sbb + (size_t)i * 4);
  float rarea = (rbox.z - rbox.x) * (rbox.w - rbox.y);
  u64 bits = 0ull;
  int jmax = NANCH - j0;
  if (jmax > 64) jmax = 64;
  for (int l = 0; l < jmax; l++) {
    int j = j0 + l;
    if (j > i) {
      float4 c = cbox[l];
      float carea = (c.z - c.x) * (c.w - c.y);
      float ltx = fmaxf(rbox.x, c.x), lty = fmaxf(rbox.y, c.y);
      float rbx = fminf(rbox.z, c.z), rby = fminf(rbox.w, c.w);
      float wx = fmaxf(rbx - ltx, 0.f);
      float wy = fmaxf(rby - lty, 0.f);
      float inter = wx * wy;
      float iou = inter / (rarea + carea - inter);  // 0/0 -> NaN -> compare false
      if (iou > 0.7f) bits |= (1ull << l);
    }
  }
  if (rb == cb) {
    maskd[((size_t)b * NW + rb) * 64 + lane] = bits;
  } else if (bits) {
    u32 idx = atomicAdd(&cnt[b * NW + cb], 1u);
    if (idx < CAP)
      lists[((size_t)(b * NW + cb)) * CAP + idx] =
          make_uint4((u32)bits, (u32)(bits >> 32), (u32)i, 0u);
  }
}

// --------------------------- NMS scan (sparse, 1 wave, no barriers) --------
// Per stripe s: cur = OR over keep-masked list entries; ctz chain over rows
// with nonzero diagonal out-edges. List head (first 64 entries) AND diagonal
// for stripe s+1 prefetched during stripe s (loop-carried registers).
__global__ __launch_bounds__(64, 1) void nms_scan_kernel(const uint4* __restrict__ lists,
                                                         const u32* __restrict__ cnt,
                                                         const u64* __restrict__ maskd,
                                                         const int* __restrict__ order,
                                                         const float* __restrict__ sb,
                                                         float* __restrict__ out) {
  int b = blockIdx.x;
  int lane = threadIdx.x;
  __shared__ u64 keep_sh[NW];
  const u64* md = maskd + (size_t)b * NW * 64;
  const uint4* lb = lists + (size_t)b * NW * CAP;

  // counts into registers: lane l holds cnt[l] and cnt[l+64]
  u32 c0 = (lane < NW) ? cnt[b * NW + lane] : 0u;
  u32 c1 = (lane + 64 < NW) ? cnt[b * NW + lane + 64] : 0u;

  u64 diag = md[lane];   // stripe 0 diagonal (coalesced)
  uint4 pf = lb[lane];   // stripe 0 list head prefetch
  for (int s = 0; s < NW; s++) {
    u64 Mw = diag;
    uint4 e0 = pf;
    if (s + 1 < NW) {
      diag = md[((s + 1) << 6) + lane];          // loop-carried prefetch
      pf = lb[(size_t)(s + 1) * CAP + lane];     // next list head in flight
    }

    int cn = (int)(u32)__builtin_amdgcn_readlane(
        (int)((s < 64) ? c0 : c1), (s < 64) ? s : s - 64);
    if (cn > CAP) cn = CAP;

    // gather: OR keep-masked list entries (first 64 from prefetch)
    u64 acc = 0ull;
    if (lane < cn) {
      u64 kw = keep_sh[e0.z >> 6];
      if ((kw >> (e0.z & 63)) & 1ull) acc |= (((u64)e0.y) << 32) | (u64)e0.x;
    }
    for (int p = lane + 64; p < cn; p += 64) {
      uint4 e = lb[(size_t)s * CAP + p];
      u64 kw = keep_sh[e.z >> 6];
      if ((kw >> (e.z & 63)) & 1ull) acc |= (((u64)e.y) << 32) | (u64)e.x;
    }
    u64 cur = waveOr64(acc);

    int nrows = NANCH - (s << 6);
    if (nrows > 64) nrows = 64;
    u64 valid = (nrows < 64) ? ((1ull << nrows) - 1ull) : ~0ull;

    // chain over rows with nonzero out-edges only
    u64 nz = __ballot(Mw != 0ull);
    u64 todo = nz & ~cur & valid;
    while (todo) {
      int t = (int)__builtin_ctzll(todo);
      cur |= bcast64(Mw, t);
      todo &= ~cur;
      todo &= ~(1ull << t);
    }
    u64 alive = (~cur) & valid;
    if (lane == 0) keep_sh[s] = alive;  // same-wave LDS, no barrier needed
  }

  // write output: out[b][orig] = kept ? sorted_box : 0
  for (int i = lane; i < NANCH; i += 64) {
    u64 kw = keep_sh[i >> 6];
    bool kept = ((kw >> (i & 63)) & 1ull) != 0ull;
    int orig = order[b * NANCH + i];
    float4 p = *(const float4*)(sb + ((size_t)b * NANCH + i) * 4);
    float4 o = kept ? p : make_float4(0.f, 0.f, 0.f, 0.f);
    *(float4*)(out + ((size_t)b * NANCH + orig) * 4) = o;
  }
}

// --------------------------- host launcher ---------------------------------

extern "C" void kernel_launch(void* const* d_in, const int* in_sizes, int n_in,
                              void* d_out, int out_size, void* d_ws, size_t ws_size,
                              hipStream_t stream) {
  const float* features = (const float*)d_in[0];
  const float* conv_w   = (const float*)d_in[1];
  const float* conv_b   = (const float*)d_in[2];
  const float* cls_w    = (const float*)d_in[3];
  const float* cls_b    = (const float*)d_in[4];
  const float* bbox_w   = (const float*)d_in[5];
  const float* bbox_b   = (const float*)d_in[6];
  const int*   img_h    = (const int*)d_in[7];
  const int*   img_w    = (const int*)d_in[8];
  float* out = (float*)d_out;
  char* ws = (char*)d_ws;

  // workspace layout (bytes); NMS arrays alias FM/WT/XP (dead by NMS time)
  const size_t OFF_FM    = 0;                  // 5,120,000
  const size_t OFF_WT    = 5120000;            // 9,437,184
  const size_t OFF_XP    = 14557184;           // 15,360,000 (ends 29,917,184)
  const size_t OFF_LISTS = 0;                  // 23,068,672 (4*88*4096*16)
  const size_t OFF_CNT   = 23068672;           // 1,408 -> pad to 23,070,208
  const size_t OFF_MASKD = 23070208;           // 180,224 (ends 23,250,432)
  const size_t OFF_X2  = 29917184;             // 5,120,000
  const size_t OFF_WCO = 35037184;             // 131,072
  const size_t OFF_BCO = 35168256;             // 256
  const size_t OFF_LOG = 35168512;             // 640,000
  const size_t OFF_SC  = 35808512;             // 90,000
  const size_t OFF_PR  = 35898512;             // 360,000
  const size_t OFF_ORD = 36258512;             // 90,000
  const size_t OFF_SB  = 36348512;             // 360,000
  const size_t WS_NEEDED = 36708512;
  if (ws_size < WS_NEEDED) return;

  float* fm   = (float*)(ws + OFF_FM);
  float* Wt   = (float*)(ws + OFF_WT);
  float* xp   = (float*)(ws + OFF_XP);
  uint4* lists = (uint4*)(ws + OFF_LISTS);
  u32*   cnt   = (u32*)(ws + OFF_CNT);
  u64*   maskd = (u64*)(ws + OFF_MASKD);
  float* x2   = (float*)(ws + OFF_X2);
  float* Wco  = (float*)(ws + OFF_WCO);
  float* bco  = (float*)(ws + OFF_BCO);
  float* logits = (float*)(ws + OFF_LOG);
  float* scores = (float*)(ws + OFF_SC);
  float* props  = (float*)(ws + OFF_PR);
  int*   order  = (int*)(ws + OFF_ORD);
  float* sb     = (float*)(ws + OFF_SB);

  // base anchors in double, rounded to f32 exactly like numpy
  BaseAnchors ba;
  {
    const double scales[3] = {64.0, 128.0, 256.0};
    const double ratios[3] = {0.5, 1.0, 2.0};
    int a = 0;
    for (int si = 0; si < 3; si++)
      for (int ri = 0; ri < 3; ri++, a++) {
        double w = scales[si] * sqrt(ratios[ri]);
        double h = scales[si] / sqrt(ratios[ri]);
        ba.x1[a] = (float)(-w / 2.0);
        ba.y1[a] = (float)(-h / 2.0);
        ba.x2[a] = (float)(w / 2.0);
        ba.y2[a] = (float)(h / 2.0);
      }
  }

  transpose_features<<<dim3(20, 16, 4), dim3(32, 8), 0, stream>>>(features, fm);
  transpose_weights<<<dim3(16, 16), 256, 0, stream>>>(conv_w, Wt);
  build_wco<<<128, 256, 0, stream>>>(cls_w, cls_b, bbox_w, bbox_b, Wco, bco);
  conv_gemm<<<dim3(40, 8, 3), 256, 0, stream>>>(fm, Wt, xp);
  combine_relu<<<1250, 256, 0, stream>>>(xp, conv_b, x2);
  gemm1x1<<<40, 256, 0, stream>>>(x2, Wco, bco, logits);
  score_box_kernel<<<88, 256, 0, stream>>>(logits, img_h, img_w, ba, scores, props);
  radix_sort_kernel<<<4, 1024, 0, stream>>>(scores, props, order, sb);
  zero_cnt<<<6, 64, 0, stream>>>(cnt);
  nms_mask_kernel<<<dim3(NW, NW, 4), 64, 0, stream>>>(sb, lists, cnt, maskd);
  nms_scan_kernel<<<4, 64, 0, stream>>>(lists, cnt, maskd, order, sb, out);
}